// Round 1
// baseline (649.047 us; speedup 1.0000x reference)
//
#include <hip/hip_runtime.h>

// Problem constants (setup_inputs is fixed): bt=64, c=64, h=w=32 -> n=1024, t=8, b=8.
#define BT 64
#define C  64
#define N  1024
#define TT 8
#define BB 8
#define SCALE 0.125f   // c^-0.5

__device__ __forceinline__ float dp4(const float a[4], const float b[4], float acc) {
    acc = fmaf(a[0], b[0], acc);
    acc = fmaf(a[1], b[1], acc);
    acc = fmaf(a[2], b[2], acc);
    acc = fmaf(a[3], b[3], acc);
    return acc;
}

// ---------------------------------------------------------------------------
// K1: qkv = W[192,64] @ x[bt][64][1024] + b  -> q,k,v token-major [bt][pos][c]
// lanes = output channel (coalesced q/k/v stores), x broadcast from LDS.
// ---------------------------------------------------------------------------
__global__ __launch_bounds__(256) void k_qkv(const float* __restrict__ x,
                                             const float* __restrict__ w,
                                             const float* __restrict__ bias,
                                             float* __restrict__ q,
                                             float* __restrict__ k,
                                             float* __restrict__ v) {
    __shared__ float xs[64][64];    // [ci][pos]  (rows 256B aligned for float4)
    __shared__ float ws[192][65];   // [o][ci], +1 pad: lane-varying o reads conflict-free
    const int bt = blockIdx.y, pos0 = blockIdx.x * 64;
    const int tid = threadIdx.x;

    for (int it = 0; it < 16; ++it) {
        int idx = it * 256 + tid;
        int ci = idx >> 6, p = idx & 63;
        xs[ci][p] = x[(bt * 64 + ci) * 1024 + pos0 + p];
    }
    for (int it = 0; it < 48; ++it) {
        int idx = it * 256 + tid;       // 12288 weights
        ws[idx / 64][idx % 64] = w[idx];
    }
    __syncthreads();

    const int oc = tid & 63, grp = tid >> 6;   // grp uniform per wave
    float accq[16], acck[16], accv[16];
    const float bq = bias[oc], bk = bias[64 + oc], bv = bias[128 + oc];
#pragma unroll
    for (int p = 0; p < 16; ++p) { accq[p] = bq; acck[p] = bk; accv[p] = bv; }

    for (int ci = 0; ci < 64; ++ci) {
        float wq = ws[oc][ci], wk = ws[64 + oc][ci], wv = ws[128 + oc][ci];
        const float4* xr = (const float4*)&xs[ci][grp * 16];  // wave-uniform -> broadcast
#pragma unroll
        for (int p4 = 0; p4 < 4; ++p4) {
            float xa[4];
            *(float4*)xa = xr[p4];
#pragma unroll
            for (int e = 0; e < 4; ++e) {
                int p = p4 * 4 + e;
                accq[p] = fmaf(wq, xa[e], accq[p]);
                acck[p] = fmaf(wk, xa[e], acck[p]);
                accv[p] = fmaf(wv, xa[e], accv[p]);
            }
        }
    }
#pragma unroll
    for (int p = 0; p < 16; ++p) {
        int pos = pos0 + grp * 16 + p;
        int base = (bt * 1024 + pos) * 64 + oc;   // coalesced over oc
        q[base] = accq[p]; k[base] = acck[p]; v[base] = accv[p];
    }
}

// ---------------------------------------------------------------------------
// K2: channel attention  cattn[bt][i][j] = softmax_j( scale * sum_pos q[pos][i]k[pos][j] )
// outer-product accumulation over pos; 64 blocks (one per bt).
// ---------------------------------------------------------------------------
__global__ __launch_bounds__(256) void k_chan(const float* __restrict__ q,
                                              const float* __restrict__ k,
                                              float* __restrict__ cattn) {
    __shared__ float qs[64][68];   // [pos][i]
    __shared__ float ks[64][68];
    __shared__ float sm[64][65];
    const int bt = blockIdx.x, tid = threadIdx.x;
    const int ti = tid >> 4, tj = tid & 15;
    float acc[4][4] = {{0.f}};

    for (int ch = 0; ch < 16; ++ch) {
        int p0 = ch * 64;
        __syncthreads();
        for (int it = 0; it < 4; ++it) {
            int idx = it * 256 + tid;
            int p = idx >> 4, c4 = idx & 15;
            *(float4*)&qs[p][c4 * 4] = *(const float4*)(q + (bt * 1024 + p0 + p) * 64 + c4 * 4);
            *(float4*)&ks[p][c4 * 4] = *(const float4*)(k + (bt * 1024 + p0 + p) * 64 + c4 * 4);
        }
        __syncthreads();
#pragma unroll 8
        for (int p = 0; p < 64; ++p) {
            float qa[4], ka[4];
            *(float4*)qa = *(const float4*)&qs[p][ti * 4];
            *(float4*)ka = *(const float4*)&ks[p][tj * 4];
#pragma unroll
            for (int r = 0; r < 4; ++r)
#pragma unroll
                for (int c = 0; c < 4; ++c)
                    acc[r][c] = fmaf(qa[r], ka[c], acc[r][c]);
        }
    }
#pragma unroll
    for (int r = 0; r < 4; ++r)
#pragma unroll
        for (int c = 0; c < 4; ++c)
            sm[ti * 4 + r][tj * 4 + c] = acc[r][c] * SCALE;
    __syncthreads();
    if (tid < 64) {
        float m = -1e30f;
        for (int j = 0; j < 64; ++j) m = fmaxf(m, sm[tid][j]);
        float s = 0.f;
        for (int j = 0; j < 64; ++j) { float e = __expf(sm[tid][j] - m); sm[tid][j] = e; s += e; }
        float inv = 1.f / s;
        for (int j = 0; j < 64; ++j) cattn[(bt * 64 + tid) * 64 + j] = sm[tid][j] * inv;
    }
}

// ---------------------------------------------------------------------------
// K3: pixel (flash-style, no max-subtract: |logits| <= ~1.3) + channel-out,
// writes xhat token-major [bt][pos][c].  64 rows x 1024 j per block.
// Row mapping interleaved (r*16+ti) so all ds_read_b128 are ~conflict-free.
// ---------------------------------------------------------------------------
__global__ __launch_bounds__(256) void k_pixel(const float* __restrict__ q,
                                               const float* __restrict__ k,
                                               const float* __restrict__ v,
                                               const float* __restrict__ cattn,
                                               float* __restrict__ xhat) {
    __shared__ float qs[64][68];
    __shared__ float ks[64][68];
    __shared__ float vs[64][68];
    __shared__ float ps[64][68];
    const int bt = blockIdx.y, row0 = blockIdx.x * 64;
    const int tid = threadIdx.x;
    const int ti = tid >> 4, tj = tid & 15;

    {   // load Q tile, pre-scaled
        const float4* src = (const float4*)(q + (bt * 1024 + row0) * 64);
        for (int it = 0; it < 4; ++it) {
            int idx = it * 256 + tid;
            int r = idx >> 4, c4 = idx & 15;
            float4 val = src[idx];
            val.x *= SCALE; val.y *= SCALE; val.z *= SCALE; val.w *= SCALE;
            *(float4*)&qs[r][c4 * 4] = val;
        }
    }

    float out[4][4] = {{0.f}};
    float lr[4] = {0.f, 0.f, 0.f, 0.f};

    for (int ch = 0; ch < 16; ++ch) {
        int j0 = ch * 64;
        __syncthreads();   // prev PV done (also covers initial qs load)
        const float4* ksrc = (const float4*)(k + (bt * 1024 + j0) * 64);
        const float4* vsrc = (const float4*)(v + (bt * 1024 + j0) * 64);
        for (int it = 0; it < 4; ++it) {
            int idx = it * 256 + tid;
            int r = idx >> 4, c4 = idx & 15;
            *(float4*)&ks[r][c4 * 4] = ksrc[idx];
            *(float4*)&vs[r][c4 * 4] = vsrc[idx];
        }
        __syncthreads();

        float s[4][4] = {{0.f}};
#pragma unroll
        for (int c4 = 0; c4 < 16; ++c4) {
            float qa[4][4], ka[4][4];
#pragma unroll
            for (int r = 0; r < 4; ++r) *(float4*)qa[r] = *(const float4*)&qs[r * 16 + ti][c4 * 4];
#pragma unroll
            for (int c = 0; c < 4; ++c) *(float4*)ka[c] = *(const float4*)&ks[c * 16 + tj][c4 * 4];
#pragma unroll
            for (int r = 0; r < 4; ++r)
#pragma unroll
                for (int c = 0; c < 4; ++c)
                    s[r][c] = dp4(qa[r], ka[c], s[r][c]);
        }
#pragma unroll
        for (int r = 0; r < 4; ++r)
#pragma unroll
            for (int c = 0; c < 4; ++c) {
                float p = __expf(s[r][c]);
                lr[r] += p;
                ps[r * 16 + ti][c * 16 + tj] = p;   // ~2-way, free
            }
        __syncthreads();
#pragma unroll
        for (int j4 = 0; j4 < 16; ++j4) {
            float pa[4][4], va[4][4];
#pragma unroll
            for (int r = 0; r < 4; ++r) *(float4*)pa[r] = *(const float4*)&ps[r * 16 + ti][j4 * 4];
#pragma unroll
            for (int e = 0; e < 4; ++e) *(float4*)va[e] = *(const float4*)&vs[j4 * 4 + e][tj * 4];
#pragma unroll
            for (int e = 0; e < 4; ++e)
#pragma unroll
                for (int r = 0; r < 4; ++r)
#pragma unroll
                    for (int c = 0; c < 4; ++c)
                        out[r][c] = fmaf(pa[r][e], va[e][c], out[r][c]);
        }
    }

    // finish softmax: reduce row-sums across the 16 tj lanes, normalize
#pragma unroll
    for (int m = 1; m < 16; m <<= 1)
#pragma unroll
        for (int r = 0; r < 4; ++r) lr[r] += __shfl_xor(lr[r], m, 64);
#pragma unroll
    for (int r = 0; r < 4; ++r) {
        float inv = 1.f / lr[r];
#pragma unroll
        for (int c = 0; c < 4; ++c) out[r][c] *= inv;
    }

    // channel-attention contribution: reuse ks as attn^T, vs as v(own rows)
    __syncthreads();
    for (int it = 0; it < 16; ++it) {
        int idx = it * 256 + tid;
        int i = idx >> 6, j = idx & 63;
        ks[j][i] = cattn[(bt * 64 + i) * 64 + j];   // transpose in LDS
    }
    {
        const float4* vsrc = (const float4*)(v + (bt * 1024 + row0) * 64);
        for (int it = 0; it < 4; ++it) {
            int idx = it * 256 + tid;
            int r = idx >> 4, c4 = idx & 15;
            *(float4*)&vs[r][c4 * 4] = vsrc[idx];
        }
    }
    __syncthreads();
#pragma unroll
    for (int j4 = 0; j4 < 16; ++j4) {
        float va[4][4], aa[4][4];
#pragma unroll
        for (int r = 0; r < 4; ++r) *(float4*)va[r] = *(const float4*)&vs[r * 16 + ti][j4 * 4];
#pragma unroll
        for (int e = 0; e < 4; ++e) *(float4*)aa[e] = *(const float4*)&ks[j4 * 4 + e][tj * 4];
#pragma unroll
        for (int e = 0; e < 4; ++e)
#pragma unroll
            for (int r = 0; r < 4; ++r)
#pragma unroll
                for (int c = 0; c < 4; ++c)
                    out[r][c] = fmaf(va[r][e], aa[e][c], out[r][c]);
    }
    // store xhat (token-major), coalesced float4
#pragma unroll
    for (int r = 0; r < 4; ++r) {
        float4 o4 = make_float4(out[r][0], out[r][1], out[r][2], out[r][3]);
        *(float4*)(xhat + (bt * 1024 + row0 + r * 16 + ti) * 64 + tj * 4) = o4;
    }
}

// ---------------------------------------------------------------------------
// K4: temporal conv (3,1,1), pad (1,0,0):
// tq/tk[bt][oc][pos] = bias[o] + sum_{ci,dt} xhat[(b,t+dt-1)][pos][ci]*w[o][ci][dt]
// lanes = pos; weights via wave-uniform scalar loads (readfirstlane).
// ---------------------------------------------------------------------------
__global__ __launch_bounds__(256) void k_tconv(const float* __restrict__ xhat,
                                               const float* __restrict__ w,
                                               const float* __restrict__ bias,
                                               float* __restrict__ tq,
                                               float* __restrict__ tk) {
    __shared__ float xs[3][64][65];
    const int bt = blockIdx.y, pos0 = blockIdx.x * 64;
    const int b = bt >> 3, t = bt & 7;
    const int tid = threadIdx.x;

    for (int dt = 0; dt < 3; ++dt) {
        int tt = t + dt - 1;
        bool ok = (tt >= 0) && (tt < 8);
        const float* src = xhat + ((b * 8 + tt) * 1024 + pos0) * 64;
        for (int it = 0; it < 16; ++it) {
            int idx = it * 256 + tid;
            int p = idx >> 6, ci = idx & 63;
            xs[dt][p][ci] = ok ? src[p * 64 + ci] : 0.f;
        }
    }
    __syncthreads();

    const int pos = tid & 63;
    const int oqu = __builtin_amdgcn_readfirstlane(tid >> 6) * 16;  // wave-uniform oc base
    float accq[16], acck[16];
#pragma unroll
    for (int oo = 0; oo < 16; ++oo) {
        accq[oo] = bias[oqu + oo];
        acck[oo] = bias[64 + oqu + oo];
    }
    for (int ci = 0; ci < 64; ++ci) {
        float x0 = xs[0][pos][ci], x1 = xs[1][pos][ci], x2 = xs[2][pos][ci];
#pragma unroll
        for (int oo = 0; oo < 16; ++oo) {
            const float* wq = w + ((oqu + oo) * 64 + ci) * 3;        // s_load (uniform)
            const float* wk = w + ((64 + oqu + oo) * 64 + ci) * 3;
            accq[oo] = fmaf(wq[0], x0, fmaf(wq[1], x1, fmaf(wq[2], x2, accq[oo])));
            acck[oo] = fmaf(wk[0], x0, fmaf(wk[1], x1, fmaf(wk[2], x2, acck[oo])));
        }
    }
#pragma unroll
    for (int oo = 0; oo < 16; ++oo) {
        int oc = oqu + oo;
        tq[(bt * 64 + oc) * 1024 + pos0 + pos] = accq[oo];  // coalesced over pos
        tk[(bt * 64 + oc) * 1024 + pos0 + pos] = acck[oo];
    }
}

// ---------------------------------------------------------------------------
// K5: temporal dots[b][i][j] = sum_{d<65536} tq[b*8+i][d] * tk[b*8+j][d]
// ---------------------------------------------------------------------------
__global__ __launch_bounds__(256) void k_tdots(const float* __restrict__ tq,
                                               const float* __restrict__ tk,
                                               float* __restrict__ td) {
    __shared__ float red[8][4];
    const int b = blockIdx.y, i = blockIdx.x;
    const int tid = threadIdx.x;
    float acc[8] = {0.f};
    const float4* qr = (const float4*)(tq + (size_t)(b * 8 + i) * 65536);
    const float4* kr = (const float4*)(tk + (size_t)(b * 8) * 65536);
    for (int it = 0; it < 64; ++it) {
        int idx = it * 256 + tid;
        float qa[4];
        *(float4*)qa = qr[idx];
#pragma unroll
        for (int j = 0; j < 8; ++j) {
            float ka[4];
            *(float4*)ka = kr[j * 16384 + idx];
            acc[j] = dp4(qa, ka, acc[j]);
        }
    }
#pragma unroll
    for (int m = 1; m < 64; m <<= 1)
#pragma unroll
        for (int j = 0; j < 8; ++j) acc[j] += __shfl_xor(acc[j], m, 64);
    int wave = tid >> 6, lane = tid & 63;
    if (lane == 0)
        for (int j = 0; j < 8; ++j) red[j][wave] = acc[j];
    __syncthreads();
    if (tid < 8)
        td[(b * 8 + i) * 8 + tid] = red[tid][0] + red[tid][1] + red[tid][2] + red[tid][3];
}

// K6: softmax over [64 rows][8] (logits O(300) -> max-subtract)
__global__ void k_tsm(const float* __restrict__ td, float* __restrict__ ta) {
    int tid = threadIdx.x;
    if (tid < 64) {
        const float* r = td + tid * 8;
        float m = r[0];
        for (int j = 1; j < 8; ++j) m = fmaxf(m, r[j]);
        float e[8], s = 0.f;
        for (int j = 0; j < 8; ++j) { e[j] = expf(r[j] - m); s += e[j]; }
        float inv = 1.f / s;
        float* o = ta + tid * 8;
        for (int j = 0; j < 8; ++j) o[j] = e[j] * inv;
    }
}

// ---------------------------------------------------------------------------
// K7: out[b*8+kk][cc][pos] = sum_t ta[b][kk][t] * v[(b*8+t)][pos][cc]
// lanes = cc for coalesced v reads; LDS transpose for coalesced stores.
// ---------------------------------------------------------------------------
__global__ __launch_bounds__(256) void k_tout(const float* __restrict__ v,
                                              const float* __restrict__ ta,
                                              float* __restrict__ outp) {
    __shared__ float ot[64][65];
    const int pt = blockIdx.x, kk = blockIdx.y, b = blockIdx.z;
    const int pos0 = pt * 64;
    const int tid = threadIdx.x;
    const int cc = tid & 63, grp = tid >> 6;
    float a[8];
#pragma unroll
    for (int t = 0; t < 8; ++t) a[t] = ta[(b * 8 + kk) * 8 + t];   // uniform -> s_load
    float acc[16] = {0.f};
#pragma unroll
    for (int t = 0; t < 8; ++t) {
        const float* vb = v + ((b * 8 + t) * 1024 + pos0) * 64 + cc;
#pragma unroll
        for (int pp = 0; pp < 16; ++pp)
            acc[pp] = fmaf(a[t], vb[(grp * 16 + pp) * 64], acc[pp]);
    }
#pragma unroll
    for (int pp = 0; pp < 16; ++pp) ot[cc][grp * 16 + pp] = acc[pp];
    __syncthreads();
    for (int it = 0; it < 16; ++it) {
        int idx = it * 256 + tid;
        int c2 = idx >> 6, p2 = idx & 63;
        outp[((b * 8 + kk) * 64 + c2) * 1024 + pos0 + p2] = ot[c2][p2];
    }
}

// ---------------------------------------------------------------------------
extern "C" void kernel_launch(void* const* d_in, const int* in_sizes, int n_in,
                              void* d_out, int out_size, void* d_ws, size_t ws_size,
                              hipStream_t stream) {
    const float* x     = (const float*)d_in[0];
    const float* qkv_w = (const float*)d_in[1];
    const float* qkv_b = (const float*)d_in[2];
    const float* tqk_w = (const float*)d_in[3];
    const float* tqk_b = (const float*)d_in[4];
    float* outp = (float*)d_out;

    // Workspace layout (floats). tq/tk alias q/k (dead after k_pixel);
    // td/ta alias cattn (dead after k_pixel). Total = 4*4194304 + 262144 fl = 68.2 MB.
    float* ws    = (float*)d_ws;
    float* q     = ws;
    float* k     = q + 4194304;
    float* v     = k + 4194304;
    float* cattn = v + 4194304;
    float* xhat  = cattn + 262144;
    float* tq    = q;             // alias
    float* tk    = k;             // alias
    float* td    = cattn;         // alias
    float* ta    = cattn + 512;   // alias

    k_qkv  <<<dim3(16, 64), 256, 0, stream>>>(x, qkv_w, qkv_b, q, k, v);
    k_chan <<<dim3(64),     256, 0, stream>>>(q, k, cattn);
    k_pixel<<<dim3(16, 64), 256, 0, stream>>>(q, k, v, cattn, xhat);
    k_tconv<<<dim3(16, 64), 256, 0, stream>>>(xhat, tqk_w, tqk_b, tq, tk);
    k_tdots<<<dim3(8, 8),   256, 0, stream>>>(tq, tk, td);
    k_tsm  <<<1, 64, 0, stream>>>(td, ta);
    k_tout <<<dim3(16, 8, 8), 256, 0, stream>>>(v, ta, outp);
}

// Round 3
// 332.915 us; speedup vs baseline: 1.9496x; 1.9496x over previous
//
#include <hip/hip_runtime.h>

// Problem constants: bt=64, c=64, h=w=32 -> n=1024, t=8, b=8.
#define SCALE 0.125f   // c^-0.5

typedef _Float16 f16;
typedef _Float16 f16x8 __attribute__((ext_vector_type(8)));
typedef float f32x4 __attribute__((ext_vector_type(4)));

#define MFMA16(A,B,C) __builtin_amdgcn_mfma_f32_16x16x32_f16(A,B,C,0,0,0)

__device__ __forceinline__ float dp4(const float a[4], const float b[4], float acc) {
    acc = fmaf(a[0], b[0], acc);
    acc = fmaf(a[1], b[1], acc);
    acc = fmaf(a[2], b[2], acc);
    acc = fmaf(a[3], b[3], acc);
    return acc;
}

// XOR swizzle for row-major [64][64] f16 tiles (128 B rows): toggles 16B slot.
__device__ __forceinline__ int sw(int row) {
    return ((row & 7) ^ ((row >> 3) & 7)) << 4;
}

// ---------------------------------------------------------------------------
// K1: qkv = W[192,64] @ x + b -> q (pre-scaled), k, v as fp16 token-major [bt][pos][c]
// ---------------------------------------------------------------------------
__global__ __launch_bounds__(256) void k_qkv(const float* __restrict__ x,
                                             const float* __restrict__ w,
                                             const float* __restrict__ bias,
                                             f16* __restrict__ q,
                                             f16* __restrict__ k,
                                             f16* __restrict__ v) {
    __shared__ float xs[64][64];
    __shared__ float ws[192][65];
    const int bt = blockIdx.y, pos0 = blockIdx.x * 64;
    const int tid = threadIdx.x;

    for (int it = 0; it < 16; ++it) {
        int idx = it * 256 + tid;
        int ci = idx >> 6, p = idx & 63;
        xs[ci][p] = x[(bt * 64 + ci) * 1024 + pos0 + p];
    }
    for (int it = 0; it < 48; ++it) {
        int idx = it * 256 + tid;
        ws[idx / 64][idx % 64] = w[idx];
    }
    __syncthreads();

    const int oc = tid & 63, grp = tid >> 6;
    float accq[16], acck[16], accv[16];
    const float bq = bias[oc], bk = bias[64 + oc], bv = bias[128 + oc];
#pragma unroll
    for (int p = 0; p < 16; ++p) { accq[p] = bq; acck[p] = bk; accv[p] = bv; }

    for (int ci = 0; ci < 64; ++ci) {
        float wq = ws[oc][ci], wk = ws[64 + oc][ci], wv = ws[128 + oc][ci];
        const float4* xr = (const float4*)&xs[ci][grp * 16];
#pragma unroll
        for (int p4 = 0; p4 < 4; ++p4) {
            float xa[4];
            *(float4*)xa = xr[p4];
#pragma unroll
            for (int e = 0; e < 4; ++e) {
                int p = p4 * 4 + e;
                accq[p] = fmaf(wq, xa[e], accq[p]);
                acck[p] = fmaf(wk, xa[e], acck[p]);
                accv[p] = fmaf(wv, xa[e], accv[p]);
            }
        }
    }
#pragma unroll
    for (int p = 0; p < 16; ++p) {
        int pos = pos0 + grp * 16 + p;
        int base = (bt * 1024 + pos) * 64 + oc;
        q[base] = (f16)(accq[p] * SCALE);   // pre-scale q
        k[base] = (f16)acck[p];
        v[base] = (f16)accv[p];
    }
}

// ---------------------------------------------------------------------------
// K2: channel attention, fp16 in -> fp16 cattn (rows already include softmax).
// q is pre-scaled so no SCALE here.
// ---------------------------------------------------------------------------
__global__ __launch_bounds__(256) void k_chan(const f16* __restrict__ q,
                                              const f16* __restrict__ k,
                                              f16* __restrict__ cattn) {
    __shared__ float qs[64][68];
    __shared__ float ks[64][68];
    __shared__ float sm[64][65];
    const int bt = blockIdx.x, tid = threadIdx.x;
    const int ti = tid >> 4, tj = tid & 15;
    float acc[4][4] = {{0.f}};

    for (int ch = 0; ch < 16; ++ch) {
        int p0 = ch * 64;
        __syncthreads();
        for (int it = 0; it < 2; ++it) {
            int e8 = it * 256 + tid;            // 512 octets of 8 f16
            int p = e8 >> 3, c8 = e8 & 7;
            f16x8 qv = *(const f16x8*)(q + (bt * 1024 + p0 + p) * 64 + c8 * 8);
            f16x8 kv = *(const f16x8*)(k + (bt * 1024 + p0 + p) * 64 + c8 * 8);
            float4 qlo = make_float4((float)qv[0], (float)qv[1], (float)qv[2], (float)qv[3]);
            float4 qhi = make_float4((float)qv[4], (float)qv[5], (float)qv[6], (float)qv[7]);
            float4 klo = make_float4((float)kv[0], (float)kv[1], (float)kv[2], (float)kv[3]);
            float4 khi = make_float4((float)kv[4], (float)kv[5], (float)kv[6], (float)kv[7]);
            *(float4*)&qs[p][c8 * 8]     = qlo;
            *(float4*)&qs[p][c8 * 8 + 4] = qhi;
            *(float4*)&ks[p][c8 * 8]     = klo;
            *(float4*)&ks[p][c8 * 8 + 4] = khi;
        }
        __syncthreads();
#pragma unroll 8
        for (int p = 0; p < 64; ++p) {
            float qa[4], ka[4];
            *(float4*)qa = *(const float4*)&qs[p][ti * 4];
            *(float4*)ka = *(const float4*)&ks[p][tj * 4];
#pragma unroll
            for (int r = 0; r < 4; ++r)
#pragma unroll
                for (int c = 0; c < 4; ++c)
                    acc[r][c] = fmaf(qa[r], ka[c], acc[r][c]);
        }
    }
#pragma unroll
    for (int r = 0; r < 4; ++r)
#pragma unroll
        for (int c = 0; c < 4; ++c)
            sm[ti * 4 + r][tj * 4 + c] = acc[r][c];
    __syncthreads();
    if (tid < 64) {
        float m = -1e30f;
        for (int j = 0; j < 64; ++j) m = fmaxf(m, sm[tid][j]);
        float s = 0.f;
        for (int j = 0; j < 64; ++j) { float e = __expf(sm[tid][j] - m); sm[tid][j] = e; s += e; }
        float inv = 1.f / s;
        for (int j = 0; j < 64; ++j) cattn[(bt * 64 + tid) * 64 + j] = (f16)(sm[tid][j] * inv);
    }
}

// ---------------------------------------------------------------------------
// K3: pixel flash attention + channel-out, fp16 MFMA, writes xhat f32 [bt][pos][c].
// Block: 4 waves, 64 rows x all 1024 j. Wave w owns rows 16w..16w+15.
// ---------------------------------------------------------------------------
__global__ __launch_bounds__(256) void k_pixel(const f16* __restrict__ q,
                                               const f16* __restrict__ k,
                                               const f16* __restrict__ v,
                                               const f16* __restrict__ cattn,
                                               float* __restrict__ xhat) {
    __shared__ f16 q_s[4096];   // [row][c] swizzled
    __shared__ f16 k_s[4096];   // [j][c] swizzled
    __shared__ f16 vt_s[4096];  // [c][j] swizzled (transposed V)
    __shared__ f16 p_s[4096];   // [row][j] swizzled

    const int bt = blockIdx.y, row0 = blockIdx.x * 64;
    const int tid = threadIdx.x;
    const int wv = tid >> 6;          // wave id
    const int ln = tid & 15;          // lane&15
    const int kgrp = (tid >> 4) & 3;  // lane>>4

    // ---- stage Q tile (rows row0..row0+63) into q_s ----
    {
        const f16* qg = q + (bt * 1024 + row0) * 64;
#pragma unroll
        for (int p = 0; p < 2; ++p) {
            int e8 = p * 256 + tid;
            int r2 = e8 >> 3, c8 = e8 & 7;
            f16x8 val = *(const f16x8*)(qg + r2 * 64 + c8 * 8);
            *(f16x8*)((char*)q_s + r2 * 128 + ((c8 * 16) ^ sw(r2))) = val;
        }
    }

    f32x4 out[4];
#pragma unroll
    for (int ct = 0; ct < 4; ++ct) out[ct] = (f32x4){0.f, 0.f, 0.f, 0.f};
    float lr[4] = {0.f, 0.f, 0.f, 0.f};

    for (int ch = 0; ch < 16; ++ch) {
        const int j0 = ch * 64;
        __syncthreads();   // prev chunk's reads of k_s/vt_s done (and q_s staged)
        {
            const f16* kg = k + (bt * 1024 + j0) * 64;
            const f16* vg = v + (bt * 1024 + j0) * 64;
#pragma unroll
            for (int p = 0; p < 2; ++p) {
                int e8 = p * 256 + tid;
                int j = e8 >> 3, c8 = e8 & 7;
                f16x8 kv = *(const f16x8*)(kg + j * 64 + c8 * 8);
                *(f16x8*)((char*)k_s + j * 128 + ((c8 * 16) ^ sw(j))) = kv;
                f16x8 vvv = *(const f16x8*)(vg + j * 64 + c8 * 8);
#pragma unroll
                for (int cc = 0; cc < 8; ++cc) {
                    int c = c8 * 8 + cc;
                    *(f16*)((char*)vt_s + c * 128 + ((j * 2) ^ sw(c))) = vvv[cc];
                }
            }
        }
        __syncthreads();

        // ---- S = Q K^T (per-wave 16x64 tile) ----
        f16x8 qa[2];
#pragma unroll
        for (int kb = 0; kb < 2; ++kb) {
            int rr = 16 * wv + ln;
            qa[kb] = *(const f16x8*)((char*)q_s + rr * 128 + (((kb * 4 + kgrp) * 16) ^ sw(rr)));
        }
        f32x4 sx[4];
#pragma unroll
        for (int jt = 0; jt < 4; ++jt) sx[jt] = (f32x4){0.f, 0.f, 0.f, 0.f};
#pragma unroll
        for (int jt = 0; jt < 4; ++jt) {
#pragma unroll
            for (int kb = 0; kb < 2; ++kb) {
                int jr = jt * 16 + ln;
                f16x8 kf = *(const f16x8*)((char*)k_s + jr * 128 + (((kb * 4 + kgrp) * 16) ^ sw(jr)));
                sx[jt] = MFMA16(qa[kb], kf, sx[jt]);
            }
        }
        // ---- exp, row-sum partials, write P (fp16) ----
#pragma unroll
        for (int jt = 0; jt < 4; ++jt) {
#pragma unroll
            for (int r = 0; r < 4; ++r) {
                float p = __expf(sx[jt][r]);
                lr[r] += p;
                int prow = 16 * wv + kgrp * 4 + r;
                int pcol = jt * 16 + ln;
                *(f16*)((char*)p_s + prow * 128 + ((pcol * 2) ^ sw(prow))) = (f16)p;
            }
        }
        __syncthreads();

        // ---- out += P V ----
        f16x8 pa[2];
#pragma unroll
        for (int kb = 0; kb < 2; ++kb) {
            int rr = 16 * wv + ln;
            pa[kb] = *(const f16x8*)((char*)p_s + rr * 128 + (((kb * 4 + kgrp) * 16) ^ sw(rr)));
        }
#pragma unroll
        for (int ct = 0; ct < 4; ++ct) {
#pragma unroll
            for (int kb = 0; kb < 2; ++kb) {
                int cr = ct * 16 + ln;
                f16x8 vf = *(const f16x8*)((char*)vt_s + cr * 128 + (((kb * 4 + kgrp) * 16) ^ sw(cr)));
                out[ct] = MFMA16(pa[kb], vf, out[ct]);
            }
        }
    }

    // ---- finish pixel softmax: reduce row-sums over the 16 col-lanes, normalize ----
#pragma unroll
    for (int mask = 1; mask < 16; mask <<= 1)
#pragma unroll
        for (int r = 0; r < 4; ++r) lr[r] += __shfl_xor(lr[r], mask, 64);
#pragma unroll
    for (int r = 0; r < 4; ++r) {
        float inv = 1.f / lr[r];
#pragma unroll
        for (int ct = 0; ct < 4; ++ct) out[ct][r] *= inv;
    }

    // ---- channel contribution: out[pos][i] += sum_jc v[pos][jc] * cattn[i][jc] ----
    __syncthreads();   // all PV reads done before restaging q_s / k_s
    {
        const f16* cg = cattn + bt * 4096;
        const f16* vg = v + (bt * 1024 + row0) * 64;
#pragma unroll
        for (int p = 0; p < 2; ++p) {
            int e8 = p * 256 + tid;
            int r2 = e8 >> 3, c8 = e8 & 7;
            f16x8 cv = *(const f16x8*)(cg + r2 * 64 + c8 * 8);
            f16x8 vv = *(const f16x8*)(vg + r2 * 64 + c8 * 8);
            int byte = r2 * 128 + ((c8 * 16) ^ sw(r2));
            *(f16x8*)((char*)k_s + byte) = cv;   // cattn rows=i
            *(f16x8*)((char*)q_s + byte) = vv;   // v own rows
        }
    }
    __syncthreads();
    {
        f16x8 va[2];
#pragma unroll
        for (int kb = 0; kb < 2; ++kb) {
            int rr = 16 * wv + ln;
            va[kb] = *(const f16x8*)((char*)q_s + rr * 128 + (((kb * 4 + kgrp) * 16) ^ sw(rr)));
        }
#pragma unroll
        for (int it = 0; it < 4; ++it) {
#pragma unroll
            for (int kb = 0; kb < 2; ++kb) {
                int ir = it * 16 + ln;
                f16x8 cb = *(const f16x8*)((char*)k_s + ir * 128 + (((kb * 4 + kgrp) * 16) ^ sw(ir)));
                out[it] = MFMA16(va[kb], cb, out[it]);
            }
        }
    }

    // ---- store xhat f32, C layout: row = 16w + kgrp*4 + r, col = ct*16 + ln ----
#pragma unroll
    for (int ct = 0; ct < 4; ++ct)
#pragma unroll
        for (int r = 0; r < 4; ++r)
            xhat[(bt * 1024 + row0 + 16 * wv + kgrp * 4 + r) * 64 + ct * 16 + ln] = out[ct][r];
}

// ---------------------------------------------------------------------------
// K4: temporal conv (3,1,1) pad (1,0,0) on f32 xhat -> tq, tk f32 [bt][oc][pos]
// ---------------------------------------------------------------------------
__global__ __launch_bounds__(256) void k_tconv(const float* __restrict__ xhat,
                                               const float* __restrict__ w,
                                               const float* __restrict__ bias,
                                               float* __restrict__ tq,
                                               float* __restrict__ tk) {
    __shared__ float xs[3][64][65];
    const int bt = blockIdx.y, pos0 = blockIdx.x * 64;
    const int b = bt >> 3, t = bt & 7;
    const int tid = threadIdx.x;

    for (int dt = 0; dt < 3; ++dt) {
        int tt = t + dt - 1;
        bool ok = (tt >= 0) && (tt < 8);
        const float* src = xhat + ((b * 8 + tt) * 1024 + pos0) * 64;
        for (int it = 0; it < 16; ++it) {
            int idx = it * 256 + tid;
            int p = idx >> 6, ci = idx & 63;
            xs[dt][p][ci] = ok ? src[p * 64 + ci] : 0.f;
        }
    }
    __syncthreads();

    const int pos = tid & 63;
    const int oqu = __builtin_amdgcn_readfirstlane(tid >> 6) * 16;
    float accq[16], acck[16];
#pragma unroll
    for (int oo = 0; oo < 16; ++oo) {
        accq[oo] = bias[oqu + oo];
        acck[oo] = bias[64 + oqu + oo];
    }
    for (int ci = 0; ci < 64; ++ci) {
        float x0 = xs[0][pos][ci], x1 = xs[1][pos][ci], x2 = xs[2][pos][ci];
#pragma unroll
        for (int oo = 0; oo < 16; ++oo) {
            const float* wq = w + ((oqu + oo) * 64 + ci) * 3;
            const float* wk = w + ((64 + oqu + oo) * 64 + ci) * 3;
            accq[oo] = fmaf(wq[0], x0, fmaf(wq[1], x1, fmaf(wq[2], x2, accq[oo])));
            acck[oo] = fmaf(wk[0], x0, fmaf(wk[1], x1, fmaf(wk[2], x2, acck[oo])));
        }
    }
#pragma unroll
    for (int oo = 0; oo < 16; ++oo) {
        int oc = oqu + oo;
        tq[(bt * 64 + oc) * 1024 + pos0 + pos] = accq[oo];
        tk[(bt * 64 + oc) * 1024 + pos0 + pos] = acck[oo];
    }
}

// ---------------------------------------------------------------------------
// K5: temporal dots partials: grid (128 d-chunks of 512, 8 b)
// partials[b][ch][i*8+j] = sum_{d in chunk} tq[b,i,d] * tk[b,j,d]
// ---------------------------------------------------------------------------
__global__ __launch_bounds__(256) void k_tdots(const float* __restrict__ tq,
                                               const float* __restrict__ tk,
                                               float* __restrict__ partials) {
    __shared__ float qs[8][516];
    __shared__ float ks[8][516];
    const int ch = blockIdx.x, b = blockIdx.y;
    const int tid = threadIdx.x;
    const int d0 = ch * 512;

    for (int it = 0; it < 4; ++it) {
        int f4 = it * 256 + tid;        // 1024 float4 per tensor
        int i = f4 >> 7, d4 = f4 & 127;
        *(float4*)&qs[i][d4 * 4] = *(const float4*)(tq + (size_t)(b * 8 + i) * 65536 + d0 + d4 * 4);
        *(float4*)&ks[i][d4 * 4] = *(const float4*)(tk + (size_t)(b * 8 + i) * 65536 + d0 + d4 * 4);
    }
    __syncthreads();

    const int p = tid >> 2, sub = tid & 3;
    const int i = p >> 3, j = p & 7;
    float acc = 0.f;
#pragma unroll 8
    for (int d4 = 0; d4 < 32; ++d4) {
        int off = (d4 * 4 + sub) * 4;
        float qa[4], ka[4];
        *(float4*)qa = *(const float4*)&qs[i][off];
        *(float4*)ka = *(const float4*)&ks[j][off];
        acc = dp4(qa, ka, acc);
    }
    acc += __shfl_xor(acc, 1, 64);
    acc += __shfl_xor(acc, 2, 64);
    if (sub == 0) partials[(b * 128 + ch) * 64 + p] = acc;
}

// K6: reduce partials + softmax over j. grid 8, 64 threads: thread = i*8+j.
__global__ void k_tsm(const float* __restrict__ partials, float* __restrict__ ta) {
    const int b = blockIdx.x, tid = threadIdx.x;
    float s = 0.f;
    for (int ch = 0; ch < 128; ++ch) s += partials[(b * 128 + ch) * 64 + tid];
    float m = s;
#pragma unroll
    for (int mask = 1; mask < 8; mask <<= 1) m = fmaxf(m, __shfl_xor(m, mask, 64));
    float e = __expf(s - m);
    float sum = e;
#pragma unroll
    for (int mask = 1; mask < 8; mask <<= 1) sum += __shfl_xor(sum, mask, 64);
    ta[b * 64 + tid] = e / sum;
}

// ---------------------------------------------------------------------------
// K7: out[b*8+kk][cc][pos] = sum_t ta[b][kk][t] * v[(b*8+t)][pos][cc]  (v fp16)
// ---------------------------------------------------------------------------
__global__ __launch_bounds__(256) void k_tout(const f16* __restrict__ v,
                                              const float* __restrict__ ta,
                                              float* __restrict__ outp) {
    __shared__ float ot[64][65];
    const int pt = blockIdx.x, kk = blockIdx.y, b = blockIdx.z;
    const int pos0 = pt * 64;
    const int tid = threadIdx.x;
    const int cc = tid & 63, grp = tid >> 6;
    float a[8];
#pragma unroll
    for (int t = 0; t < 8; ++t) a[t] = ta[(b * 8 + kk) * 8 + t];
    float acc[16] = {0.f};
#pragma unroll
    for (int t = 0; t < 8; ++t) {
        const f16* vb = v + ((size_t)(b * 8 + t) * 1024 + pos0) * 64 + cc;
#pragma unroll
        for (int pp = 0; pp < 16; ++pp)
            acc[pp] = fmaf(a[t], (float)vb[(grp * 16 + pp) * 64], acc[pp]);
    }
#pragma unroll
    for (int pp = 0; pp < 16; ++pp) ot[cc][grp * 16 + pp] = acc[pp];
    __syncthreads();
    for (int it = 0; it < 16; ++it) {
        int idx = it * 256 + tid;
        int c2 = idx >> 6, p2 = idx & 63;
        outp[((b * 8 + kk) * 64 + c2) * 1024 + pos0 + p2] = ot[c2][p2];
    }
}

// ---------------------------------------------------------------------------
extern "C" void kernel_launch(void* const* d_in, const int* in_sizes, int n_in,
                              void* d_out, int out_size, void* d_ws, size_t ws_size,
                              hipStream_t stream) {
    const float* x     = (const float*)d_in[0];
    const float* qkv_w = (const float*)d_in[1];
    const float* qkv_b = (const float*)d_in[2];
    const float* tqk_w = (const float*)d_in[3];
    const float* tqk_b = (const float*)d_in[4];
    float* outp = (float*)d_out;

    // ws layout (bytes):
    // [0,8M)   q fp16        -> later overlaid by tq f32 [0,16M)
    // [8M,16M) k fp16
    // [16M,24M) v fp16       (live until k_tout)
    // [24M,24.5M) cattn fp16
    // [24.5M,24.75M) partials f32 (256KB)
    // [24.75M,+2KB) ta f32
    // [25M,41M) xhat f32
    // [41M,57M) tk f32
    char* wsb = (char*)d_ws;
    f16*   q        = (f16*)wsb;
    f16*   k        = (f16*)(wsb + (8u << 20));
    f16*   v        = (f16*)(wsb + (16u << 20));
    f16*   cattn    = (f16*)(wsb + (24u << 20));
    float* partials = (float*)(wsb + (24u << 20) + (1u << 19));
    float* ta       = (float*)(wsb + (24u << 20) + (1u << 19) + (1u << 18));
    float* xhat     = (float*)(wsb + (25u << 20));
    float* tq       = (float*)wsb;                 // overlays q,k (dead after k_pixel)
    float* tk       = (float*)(wsb + (41u << 20));

    k_qkv  <<<dim3(16, 64), 256, 0, stream>>>(x, qkv_w, qkv_b, q, k, v);
    k_chan <<<dim3(64),     256, 0, stream>>>(q, k, cattn);
    k_pixel<<<dim3(16, 64), 256, 0, stream>>>(q, k, v, cattn, xhat);
    k_tconv<<<dim3(16, 64), 256, 0, stream>>>(xhat, tqk_w, tqk_b, tq, tk);
    k_tdots<<<dim3(128, 8), 256, 0, stream>>>(tq, tk, partials);
    k_tsm  <<<dim3(8), 64, 0, stream>>>(partials, ta);
    k_tout <<<dim3(16, 8, 8), 256, 0, stream>>>(v, ta, outp);
}

// Round 4
// 231.824 us; speedup vs baseline: 2.7997x; 1.4361x over previous
//
#include <hip/hip_runtime.h>

// Problem constants: bt=64, c=64, h=w=32 -> n=1024, t=8, b=8.
#define SCALE 0.125f   // c^-0.5

typedef _Float16 f16;
typedef _Float16 f16x8 __attribute__((ext_vector_type(8)));
typedef float f32x4 __attribute__((ext_vector_type(4)));

#define MFMA16(A,B,C) __builtin_amdgcn_mfma_f32_16x16x32_f16(A,B,C,0,0,0)

__device__ __forceinline__ float dp4(const float a[4], const float b[4], float acc) {
    acc = fmaf(a[0], b[0], acc);
    acc = fmaf(a[1], b[1], acc);
    acc = fmaf(a[2], b[2], acc);
    acc = fmaf(a[3], b[3], acc);
    return acc;
}

// XOR swizzle for row-major [64][64] f16 tiles (128 B rows): toggles 16B slot.
__device__ __forceinline__ int sw(int row) {
    return ((row & 7) ^ ((row >> 3) & 7)) << 4;
}

// ---------------------------------------------------------------------------
// K1: qkv = W[192,64] @ x + b -> q (pre-scaled), k, v as fp16 token-major [bt][pos][c]
// ---------------------------------------------------------------------------
__global__ __launch_bounds__(256) void k_qkv(const float* __restrict__ x,
                                             const float* __restrict__ w,
                                             const float* __restrict__ bias,
                                             f16* __restrict__ q,
                                             f16* __restrict__ k,
                                             f16* __restrict__ v) {
    __shared__ float xs[64][64];
    __shared__ float ws[192][65];
    const int bt = blockIdx.y, pos0 = blockIdx.x * 64;
    const int tid = threadIdx.x;

    for (int it = 0; it < 16; ++it) {
        int idx = it * 256 + tid;
        int ci = idx >> 6, p = idx & 63;
        xs[ci][p] = x[(bt * 64 + ci) * 1024 + pos0 + p];
    }
    for (int it = 0; it < 48; ++it) {
        int idx = it * 256 + tid;
        ws[idx / 64][idx % 64] = w[idx];
    }
    __syncthreads();

    const int oc = tid & 63, grp = tid >> 6;
    float accq[16], acck[16], accv[16];
    const float bq = bias[oc], bk = bias[64 + oc], bv = bias[128 + oc];
#pragma unroll
    for (int p = 0; p < 16; ++p) { accq[p] = bq; acck[p] = bk; accv[p] = bv; }

    for (int ci = 0; ci < 64; ++ci) {
        float wq = ws[oc][ci], wk = ws[64 + oc][ci], wv = ws[128 + oc][ci];
        const float4* xr = (const float4*)&xs[ci][grp * 16];
#pragma unroll
        for (int p4 = 0; p4 < 4; ++p4) {
            float xa[4];
            *(float4*)xa = xr[p4];
#pragma unroll
            for (int e = 0; e < 4; ++e) {
                int p = p4 * 4 + e;
                accq[p] = fmaf(wq, xa[e], accq[p]);
                acck[p] = fmaf(wk, xa[e], acck[p]);
                accv[p] = fmaf(wv, xa[e], accv[p]);
            }
        }
    }
#pragma unroll
    for (int p = 0; p < 16; ++p) {
        int pos = pos0 + grp * 16 + p;
        int base = (bt * 1024 + pos) * 64 + oc;
        q[base] = (f16)(accq[p] * SCALE);   // pre-scale q
        k[base] = (f16)acck[p];
        v[base] = (f16)accv[p];
    }
}

// ---------------------------------------------------------------------------
// K2: channel attention, fp16 in -> fp16 cattn (rows already include softmax).
// ---------------------------------------------------------------------------
__global__ __launch_bounds__(256) void k_chan(const f16* __restrict__ q,
                                              const f16* __restrict__ k,
                                              f16* __restrict__ cattn) {
    __shared__ float qs[64][68];
    __shared__ float ks[64][68];
    __shared__ float sm[64][65];
    const int bt = blockIdx.x, tid = threadIdx.x;
    const int ti = tid >> 4, tj = tid & 15;
    float acc[4][4] = {{0.f}};

    for (int ch = 0; ch < 16; ++ch) {
        int p0 = ch * 64;
        __syncthreads();
        for (int it = 0; it < 2; ++it) {
            int e8 = it * 256 + tid;            // 512 octets of 8 f16
            int p = e8 >> 3, c8 = e8 & 7;
            f16x8 qv = *(const f16x8*)(q + (bt * 1024 + p0 + p) * 64 + c8 * 8);
            f16x8 kv = *(const f16x8*)(k + (bt * 1024 + p0 + p) * 64 + c8 * 8);
            float4 qlo = make_float4((float)qv[0], (float)qv[1], (float)qv[2], (float)qv[3]);
            float4 qhi = make_float4((float)qv[4], (float)qv[5], (float)qv[6], (float)qv[7]);
            float4 klo = make_float4((float)kv[0], (float)kv[1], (float)kv[2], (float)kv[3]);
            float4 khi = make_float4((float)kv[4], (float)kv[5], (float)kv[6], (float)kv[7]);
            *(float4*)&qs[p][c8 * 8]     = qlo;
            *(float4*)&qs[p][c8 * 8 + 4] = qhi;
            *(float4*)&ks[p][c8 * 8]     = klo;
            *(float4*)&ks[p][c8 * 8 + 4] = khi;
        }
        __syncthreads();
#pragma unroll 8
        for (int p = 0; p < 64; ++p) {
            float qa[4], ka[4];
            *(float4*)qa = *(const float4*)&qs[p][ti * 4];
            *(float4*)ka = *(const float4*)&ks[p][tj * 4];
#pragma unroll
            for (int r = 0; r < 4; ++r)
#pragma unroll
                for (int c = 0; c < 4; ++c)
                    acc[r][c] = fmaf(qa[r], ka[c], acc[r][c]);
        }
    }
#pragma unroll
    for (int r = 0; r < 4; ++r)
#pragma unroll
        for (int c = 0; c < 4; ++c)
            sm[ti * 4 + r][tj * 4 + c] = acc[r][c];
    __syncthreads();
    if (tid < 64) {
        float m = -1e30f;
        for (int j = 0; j < 64; ++j) m = fmaxf(m, sm[tid][j]);
        float s = 0.f;
        for (int j = 0; j < 64; ++j) { float e = __expf(sm[tid][j] - m); sm[tid][j] = e; s += e; }
        float inv = 1.f / s;
        for (int j = 0; j < 64; ++j) cattn[(bt * 64 + tid) * 64 + j] = (f16)(sm[tid][j] * inv);
    }
}

// ---------------------------------------------------------------------------
// K3: pixel flash attention + channel-out, fp16 MFMA.
// Writes xhat as SPLIT fp16 (hi + lo), token-major [bt][pos][c].
// ---------------------------------------------------------------------------
__global__ __launch_bounds__(256) void k_pixel(const f16* __restrict__ q,
                                               const f16* __restrict__ k,
                                               const f16* __restrict__ v,
                                               const f16* __restrict__ cattn,
                                               f16* __restrict__ xh,
                                               f16* __restrict__ xl) {
    __shared__ f16 q_s[4096];   // [row][c] swizzled
    __shared__ f16 k_s[4096];   // [j][c] swizzled
    __shared__ f16 vt_s[4096];  // [c][j] swizzled (transposed V)
    __shared__ f16 p_s[4096];   // [row][j] swizzled

    const int bt = blockIdx.y, row0 = blockIdx.x * 64;
    const int tid = threadIdx.x;
    const int wv = tid >> 6;          // wave id
    const int ln = tid & 15;          // lane&15
    const int kgrp = (tid >> 4) & 3;  // lane>>4

    // ---- stage Q tile (rows row0..row0+63) into q_s ----
    {
        const f16* qg = q + (bt * 1024 + row0) * 64;
#pragma unroll
        for (int p = 0; p < 2; ++p) {
            int e8 = p * 256 + tid;
            int r2 = e8 >> 3, c8 = e8 & 7;
            f16x8 val = *(const f16x8*)(qg + r2 * 64 + c8 * 8);
            *(f16x8*)((char*)q_s + r2 * 128 + ((c8 * 16) ^ sw(r2))) = val;
        }
    }

    f32x4 out[4];
#pragma unroll
    for (int ct = 0; ct < 4; ++ct) out[ct] = (f32x4){0.f, 0.f, 0.f, 0.f};
    float lr[4] = {0.f, 0.f, 0.f, 0.f};

    for (int ch = 0; ch < 16; ++ch) {
        const int j0 = ch * 64;
        __syncthreads();   // prev chunk's reads of k_s/vt_s done (and q_s staged)
        {
            const f16* kg = k + (bt * 1024 + j0) * 64;
            const f16* vg = v + (bt * 1024 + j0) * 64;
#pragma unroll
            for (int p = 0; p < 2; ++p) {
                int e8 = p * 256 + tid;
                int j = e8 >> 3, c8 = e8 & 7;
                f16x8 kv = *(const f16x8*)(kg + j * 64 + c8 * 8);
                *(f16x8*)((char*)k_s + j * 128 + ((c8 * 16) ^ sw(j))) = kv;
                f16x8 vvv = *(const f16x8*)(vg + j * 64 + c8 * 8);
#pragma unroll
                for (int cc = 0; cc < 8; ++cc) {
                    int c = c8 * 8 + cc;
                    *(f16*)((char*)vt_s + c * 128 + ((j * 2) ^ sw(c))) = vvv[cc];
                }
            }
        }
        __syncthreads();

        // ---- S = Q K^T (per-wave 16x64 tile) ----
        f16x8 qa[2];
#pragma unroll
        for (int kb = 0; kb < 2; ++kb) {
            int rr = 16 * wv + ln;
            qa[kb] = *(const f16x8*)((char*)q_s + rr * 128 + (((kb * 4 + kgrp) * 16) ^ sw(rr)));
        }
        f32x4 sx[4];
#pragma unroll
        for (int jt = 0; jt < 4; ++jt) sx[jt] = (f32x4){0.f, 0.f, 0.f, 0.f};
#pragma unroll
        for (int jt = 0; jt < 4; ++jt) {
#pragma unroll
            for (int kb = 0; kb < 2; ++kb) {
                int jr = jt * 16 + ln;
                f16x8 kf = *(const f16x8*)((char*)k_s + jr * 128 + (((kb * 4 + kgrp) * 16) ^ sw(jr)));
                sx[jt] = MFMA16(qa[kb], kf, sx[jt]);
            }
        }
        // ---- exp, row-sum partials, write P (fp16) ----
#pragma unroll
        for (int jt = 0; jt < 4; ++jt) {
#pragma unroll
            for (int r = 0; r < 4; ++r) {
                float p = __expf(sx[jt][r]);
                lr[r] += p;
                int prow = 16 * wv + kgrp * 4 + r;
                int pcol = jt * 16 + ln;
                *(f16*)((char*)p_s + prow * 128 + ((pcol * 2) ^ sw(prow))) = (f16)p;
            }
        }
        __syncthreads();

        // ---- out += P V ----
        f16x8 pa[2];
#pragma unroll
        for (int kb = 0; kb < 2; ++kb) {
            int rr = 16 * wv + ln;
            pa[kb] = *(const f16x8*)((char*)p_s + rr * 128 + (((kb * 4 + kgrp) * 16) ^ sw(rr)));
        }
#pragma unroll
        for (int ct = 0; ct < 4; ++ct) {
#pragma unroll
            for (int kb = 0; kb < 2; ++kb) {
                int cr = ct * 16 + ln;
                f16x8 vf = *(const f16x8*)((char*)vt_s + cr * 128 + (((kb * 4 + kgrp) * 16) ^ sw(cr)));
                out[ct] = MFMA16(pa[kb], vf, out[ct]);
            }
        }
    }

    // ---- finish pixel softmax: reduce row-sums over the 16 col-lanes, normalize ----
#pragma unroll
    for (int mask = 1; mask < 16; mask <<= 1)
#pragma unroll
        for (int r = 0; r < 4; ++r) lr[r] += __shfl_xor(lr[r], mask, 64);
#pragma unroll
    for (int r = 0; r < 4; ++r) {
        float inv = 1.f / lr[r];
#pragma unroll
        for (int ct = 0; ct < 4; ++ct) out[ct][r] *= inv;
    }

    // ---- channel contribution: out[pos][i] += sum_jc v[pos][jc] * cattn[i][jc] ----
    __syncthreads();   // all PV reads done before restaging q_s / k_s
    {
        const f16* cg = cattn + bt * 4096;
        const f16* vg = v + (bt * 1024 + row0) * 64;
#pragma unroll
        for (int p = 0; p < 2; ++p) {
            int e8 = p * 256 + tid;
            int r2 = e8 >> 3, c8 = e8 & 7;
            f16x8 cv = *(const f16x8*)(cg + r2 * 64 + c8 * 8);
            f16x8 vv = *(const f16x8*)(vg + r2 * 64 + c8 * 8);
            int byte = r2 * 128 + ((c8 * 16) ^ sw(r2));
            *(f16x8*)((char*)k_s + byte) = cv;   // cattn rows=i
            *(f16x8*)((char*)q_s + byte) = vv;   // v own rows
        }
    }
    __syncthreads();
    {
        f16x8 va[2];
#pragma unroll
        for (int kb = 0; kb < 2; ++kb) {
            int rr = 16 * wv + ln;
            va[kb] = *(const f16x8*)((char*)q_s + rr * 128 + (((kb * 4 + kgrp) * 16) ^ sw(rr)));
        }
#pragma unroll
        for (int it = 0; it < 4; ++it) {
#pragma unroll
            for (int kb = 0; kb < 2; ++kb) {
                int ir = it * 16 + ln;
                f16x8 cb = *(const f16x8*)((char*)k_s + ir * 128 + (((kb * 4 + kgrp) * 16) ^ sw(ir)));
                out[it] = MFMA16(va[kb], cb, out[it]);
            }
        }
    }

    // ---- store xhat as split fp16: hi + residual lo ----
#pragma unroll
    for (int ct = 0; ct < 4; ++ct)
#pragma unroll
        for (int r = 0; r < 4; ++r) {
            float val = out[ct][r];
            f16 h = (f16)val;
            int idx = (bt * 1024 + row0 + 16 * wv + kgrp * 4 + r) * 64 + ct * 16 + ln;
            xh[idx] = h;
            xl[idx] = (f16)(val - (float)h);
        }
}

// ---------------------------------------------------------------------------
// K4: temporal conv (3,1,1) pad (1,0,0) as split-fp16 MFMA GEMM:
//   C[pos 64][oc 128] = X[pos][cidt 192] * W^T, per (b,t,pos-tile)
//   C = Ah*Bh + Al*Bh + Ah*Bl  (22-bit effective mantissa, f32 accumulate)
// K order: cidt = dt*64 + ci. Weights loaded once per block into VGPR frags.
// ---------------------------------------------------------------------------
__global__ __launch_bounds__(256) void k_tconv(const f16* __restrict__ xh,
                                               const f16* __restrict__ xl,
                                               const float* __restrict__ w,
                                               const float* __restrict__ bias,
                                               float* __restrict__ tq,
                                               float* __restrict__ tk) {
    __shared__ f16 xs[2][3][4096];   // [hiLo][dt][row*64+ci] swizzled rows, 48KB
    const int bt = blockIdx.y, pos0 = blockIdx.x * 64;
    const int b = bt >> 3, t = bt & 7;
    const int tid = threadIdx.x;
    const int wvid = tid >> 6, ln = tid & 15, kgrp = (tid >> 4) & 3;

    // ---- stage xhat hi/lo tiles for dt = 0..2 (zero-fill at temporal edges) ----
    for (int dt = 0; dt < 3; ++dt) {
        int tt = t + dt - 1;
        bool ok = (tt >= 0) && (tt < 8);
        const f16* srch = xh + ((b * 8 + tt) * 1024 + pos0) * 64;
        const f16* srcl = xl + ((b * 8 + tt) * 1024 + pos0) * 64;
#pragma unroll
        for (int p = 0; p < 2; ++p) {
            int e8 = p * 256 + tid;
            int r2 = e8 >> 3, c8 = e8 & 7;
            f16x8 vh = {0, 0, 0, 0, 0, 0, 0, 0};
            f16x8 vl = {0, 0, 0, 0, 0, 0, 0, 0};
            if (ok) {
                vh = *(const f16x8*)(srch + r2 * 64 + c8 * 8);
                vl = *(const f16x8*)(srcl + r2 * 64 + c8 * 8);
            }
            int byte = r2 * 128 + ((c8 * 16) ^ sw(r2));
            *(f16x8*)((char*)&xs[0][dt][0] + byte) = vh;
            *(f16x8*)((char*)&xs[1][dt][0] + byte) = vl;
        }
    }

    // ---- load W fragments (one-time): wave covers ocs wvid*32 .. wvid*32+31 ----
    // B frag layout: col(oc) = ln, K element = kgrp*8 + j within 32-chunk kc.
    f16x8 bh[2][6], bl[2][6];
#pragma unroll
    for (int og = 0; og < 2; ++og) {
        int oc = wvid * 32 + og * 16 + ln;    // 0..127 (0-63 -> tq, 64-127 -> tk)
#pragma unroll
        for (int kc = 0; kc < 6; ++kc) {
            f16x8 hbuf, lbuf;
#pragma unroll
            for (int j = 0; j < 8; ++j) {
                int K = kc * 32 + kgrp * 8 + j;
                int dt = K >> 6, ci = K & 63;
                float wf = w[(oc * 64 + ci) * 3 + dt];
                f16 h = (f16)wf;
                hbuf[j] = h;
                lbuf[j] = (f16)(wf - (float)h);
            }
            bh[og][kc] = hbuf;
            bl[og][kc] = lbuf;
        }
    }
    __syncthreads();

    // ---- 4 pos-groups of 16; per group: load A frags, 2 oc-groups x 18 MFMA ----
#pragma unroll
    for (int pg = 0; pg < 4; ++pg) {
        f16x8 ah[6], al[6];
        int rr = pg * 16 + ln;
#pragma unroll
        for (int kc = 0; kc < 6; ++kc) {
            int dt = kc >> 1;
            int ci0 = (kc & 1) * 32 + kgrp * 8;
            int byte = rr * 128 + ((ci0 * 2) ^ sw(rr));
            ah[kc] = *(const f16x8*)((char*)&xs[0][dt][0] + byte);
            al[kc] = *(const f16x8*)((char*)&xs[1][dt][0] + byte);
        }
#pragma unroll
        for (int og = 0; og < 2; ++og) {
            int oc = wvid * 32 + og * 16 + ln;   // C col = ln -> same oc as B frag
            float bv = bias[oc];
            f32x4 acc = {bv, bv, bv, bv};
#pragma unroll
            for (int kc = 0; kc < 6; ++kc) {
                acc = MFMA16(ah[kc], bh[og][kc], acc);
                acc = MFMA16(al[kc], bh[og][kc], acc);
                acc = MFMA16(ah[kc], bl[og][kc], acc);
            }
            // C: pos = pos0 + pg*16 + kgrp*4 + r, oc col = ln
            float* dst = (oc < 64) ? tq : tk;
            int orow = oc & 63;
            int pos = pos0 + pg * 16 + kgrp * 4;
            *(float4*)&dst[(bt * 64 + orow) * 1024 + pos] =
                make_float4(acc[0], acc[1], acc[2], acc[3]);
        }
    }
}

// ---------------------------------------------------------------------------
// K5: temporal dots partials: grid (128 d-chunks of 512, 8 b)
// ---------------------------------------------------------------------------
__global__ __launch_bounds__(256) void k_tdots(const float* __restrict__ tq,
                                               const float* __restrict__ tk,
                                               float* __restrict__ partials) {
    __shared__ float qs[8][516];
    __shared__ float ks[8][516];
    const int ch = blockIdx.x, b = blockIdx.y;
    const int tid = threadIdx.x;
    const int d0 = ch * 512;

    for (int it = 0; it < 4; ++it) {
        int f4 = it * 256 + tid;        // 1024 float4 per tensor
        int i = f4 >> 7, d4 = f4 & 127;
        *(float4*)&qs[i][d4 * 4] = *(const float4*)(tq + (size_t)(b * 8 + i) * 65536 + d0 + d4 * 4);
        *(float4*)&ks[i][d4 * 4] = *(const float4*)(tk + (size_t)(b * 8 + i) * 65536 + d0 + d4 * 4);
    }
    __syncthreads();

    const int p = tid >> 2, sub = tid & 3;
    const int i = p >> 3, j = p & 7;
    float acc = 0.f;
#pragma unroll 8
    for (int d4 = 0; d4 < 32; ++d4) {
        int off = (d4 * 4 + sub) * 4;
        float qa[4], ka[4];
        *(float4*)qa = *(const float4*)&qs[i][off];
        *(float4*)ka = *(const float4*)&ks[j][off];
        acc = dp4(qa, ka, acc);
    }
    acc += __shfl_xor(acc, 1, 64);
    acc += __shfl_xor(acc, 2, 64);
    if (sub == 0) partials[(b * 128 + ch) * 64 + p] = acc;
}

// K6: reduce partials + softmax over j. grid 8, 64 threads: thread = i*8+j.
__global__ void k_tsm(const float* __restrict__ partials, float* __restrict__ ta) {
    const int b = blockIdx.x, tid = threadIdx.x;
    float s = 0.f;
    for (int ch = 0; ch < 128; ++ch) s += partials[(b * 128 + ch) * 64 + tid];
    float m = s;
#pragma unroll
    for (int mask = 1; mask < 8; mask <<= 1) m = fmaxf(m, __shfl_xor(m, mask, 64));
    float e = __expf(s - m);
    float sum = e;
#pragma unroll
    for (int mask = 1; mask < 8; mask <<= 1) sum += __shfl_xor(sum, mask, 64);
    ta[b * 64 + tid] = e / sum;
}

// ---------------------------------------------------------------------------
// K7: out[b*8+kk][cc][pos] = sum_t ta[b][kk][t] * v[(b*8+t)][pos][cc]  (v fp16)
// ---------------------------------------------------------------------------
__global__ __launch_bounds__(256) void k_tout(const f16* __restrict__ v,
                                              const float* __restrict__ ta,
                                              float* __restrict__ outp) {
    __shared__ float ot[64][65];
    const int pt = blockIdx.x, kk = blockIdx.y, b = blockIdx.z;
    const int pos0 = pt * 64;
    const int tid = threadIdx.x;
    const int cc = tid & 63, grp = tid >> 6;
    float a[8];
#pragma unroll
    for (int t = 0; t < 8; ++t) a[t] = ta[(b * 8 + kk) * 8 + t];
    float acc[16] = {0.f};
#pragma unroll
    for (int t = 0; t < 8; ++t) {
        const f16* vb = v + ((size_t)(b * 8 + t) * 1024 + pos0) * 64 + cc;
#pragma unroll
        for (int pp = 0; pp < 16; ++pp)
            acc[pp] = fmaf(a[t], (float)vb[(grp * 16 + pp) * 64], acc[pp]);
    }
#pragma unroll
    for (int pp = 0; pp < 16; ++pp) ot[cc][grp * 16 + pp] = acc[pp];
    __syncthreads();
    for (int it = 0; it < 16; ++it) {
        int idx = it * 256 + tid;
        int c2 = idx >> 6, p2 = idx & 63;
        outp[((b * 8 + kk) * 64 + c2) * 1024 + pos0 + p2] = ot[c2][p2];
    }
}

// ---------------------------------------------------------------------------
extern "C" void kernel_launch(void* const* d_in, const int* in_sizes, int n_in,
                              void* d_out, int out_size, void* d_ws, size_t ws_size,
                              hipStream_t stream) {
    const float* x     = (const float*)d_in[0];
    const float* qkv_w = (const float*)d_in[1];
    const float* qkv_b = (const float*)d_in[2];
    const float* tqk_w = (const float*)d_in[3];
    const float* tqk_b = (const float*)d_in[4];
    float* outp = (float*)d_out;

    // ws layout (bytes):
    // [0,8M)   q fp16        -> later overlaid by tq f32 [0,16M)
    // [8M,16M) k fp16
    // [16M,24M) v fp16       (live until k_tout)
    // [24M,24.5M) cattn fp16
    // [24.5M,24.75M) partials f32 (256KB)
    // [24.75M,+2KB) ta f32
    // [25M,33M) xhat_hi fp16
    // [33M,41M) xhat_lo fp16
    // [41M,57M) tk f32
    char* wsb = (char*)d_ws;
    f16*   q        = (f16*)wsb;
    f16*   k        = (f16*)(wsb + (8u << 20));
    f16*   v        = (f16*)(wsb + (16u << 20));
    f16*   cattn    = (f16*)(wsb + (24u << 20));
    float* partials = (float*)(wsb + (24u << 20) + (1u << 19));
    float* ta       = (float*)(wsb + (24u << 20) + (1u << 19) + (1u << 18));
    f16*   xhat_hi  = (f16*)(wsb + (25u << 20));
    f16*   xhat_lo  = (f16*)(wsb + (33u << 20));
    float* tq       = (float*)wsb;                 // overlays q,k (dead after k_pixel)
    float* tk       = (float*)(wsb + (41u << 20));

    k_qkv  <<<dim3(16, 64), 256, 0, stream>>>(x, qkv_w, qkv_b, q, k, v);
    k_chan <<<dim3(64),     256, 0, stream>>>(q, k, cattn);
    k_pixel<<<dim3(16, 64), 256, 0, stream>>>(q, k, v, cattn, xhat_hi, xhat_lo);
    k_tconv<<<dim3(16, 64), 256, 0, stream>>>(xhat_hi, xhat_lo, tqk_w, tqk_b, tq, tk);
    k_tdots<<<dim3(128, 8), 256, 0, stream>>>(tq, tk, partials);
    k_tsm  <<<dim3(8), 64, 0, stream>>>(partials, ta);
    k_tout <<<dim3(16, 8, 8), 256, 0, stream>>>(v, ta, outp);
}

// Round 5
// 231.486 us; speedup vs baseline: 2.8038x; 1.0015x over previous
//
#include <hip/hip_runtime.h>

// Problem constants: bt=64, c=64, h=w=32 -> n=1024, t=8, b=8.
#define SCALE 0.125f   // c^-0.5

typedef _Float16 f16;
typedef _Float16 f16x8 __attribute__((ext_vector_type(8)));
typedef float f32x4 __attribute__((ext_vector_type(4)));

#define MFMA16(A,B,C) __builtin_amdgcn_mfma_f32_16x16x32_f16(A,B,C,0,0,0)

__device__ __forceinline__ float dp4(const float a[4], const float b[4], float acc) {
    acc = fmaf(a[0], b[0], acc);
    acc = fmaf(a[1], b[1], acc);
    acc = fmaf(a[2], b[2], acc);
    acc = fmaf(a[3], b[3], acc);
    return acc;
}

// XOR swizzle for row-major 128B-row f16 tiles: toggles 16B slot.
__device__ __forceinline__ int sw(int row) {
    return ((row & 7) ^ ((row >> 3) & 7)) << 4;
}

// ---------------------------------------------------------------------------
// K1: qkv = W[192,64] @ x + b -> q (pre-scaled), k, v fp16 token-major [bt][pos][c]
//     + vt fp16 channel-major [bt][c][pos] (LDS-transposed v)
// ---------------------------------------------------------------------------
__global__ __launch_bounds__(256) void k_qkv(const float* __restrict__ x,
                                             const float* __restrict__ w,
                                             const float* __restrict__ bias,
                                             f16* __restrict__ q,
                                             f16* __restrict__ k,
                                             f16* __restrict__ v,
                                             f16* __restrict__ vt) {
    __shared__ float xs[64][64];
    __shared__ float ws[192][65];
    __shared__ f16 vts[4096];        // [oc][pos] swizzled 128B rows
    const int bt = blockIdx.y, pos0 = blockIdx.x * 64;
    const int tid = threadIdx.x;

    for (int it = 0; it < 16; ++it) {
        int idx = it * 256 + tid;
        int ci = idx >> 6, p = idx & 63;
        xs[ci][p] = x[(bt * 64 + ci) * 1024 + pos0 + p];
    }
    for (int it = 0; it < 48; ++it) {
        int idx = it * 256 + tid;
        ws[idx / 64][idx % 64] = w[idx];
    }
    __syncthreads();

    const int oc = tid & 63, grp = tid >> 6;
    float accq[16], acck[16], accv[16];
    const float bq = bias[oc], bk = bias[64 + oc], bv = bias[128 + oc];
#pragma unroll
    for (int p = 0; p < 16; ++p) { accq[p] = bq; acck[p] = bk; accv[p] = bv; }

    for (int ci = 0; ci < 64; ++ci) {
        float wq = ws[oc][ci], wk = ws[64 + oc][ci], wv = ws[128 + oc][ci];
        const float4* xr = (const float4*)&xs[ci][grp * 16];
#pragma unroll
        for (int p4 = 0; p4 < 4; ++p4) {
            float xa[4];
            *(float4*)xa = xr[p4];
#pragma unroll
            for (int e = 0; e < 4; ++e) {
                int p = p4 * 4 + e;
                accq[p] = fmaf(wq, xa[e], accq[p]);
                acck[p] = fmaf(wk, xa[e], acck[p]);
                accv[p] = fmaf(wv, xa[e], accv[p]);
            }
        }
    }
#pragma unroll
    for (int p = 0; p < 16; ++p) {
        int pos = pos0 + grp * 16 + p;
        int base = (bt * 1024 + pos) * 64 + oc;
        f16 vh = (f16)accv[p];
        q[base] = (f16)(accq[p] * SCALE);   // pre-scale q
        k[base] = (f16)acck[p];
        v[base] = vh;
        // stash v^T tile in LDS: row = oc, col = grp*16+p
        int col = grp * 16 + p;
        *(f16*)((char*)vts + oc * 128 + ((col * 2) ^ sw(oc))) = vh;
    }
    __syncthreads();
    // write vt[bt][oc][pos0..pos0+63], coalesced f16x8
#pragma unroll
    for (int it = 0; it < 2; ++it) {
        int s = it * 256 + tid;
        int row = s >> 3, c8 = s & 7;
        f16x8 val = *(const f16x8*)((char*)vts + row * 128 + ((c8 * 16) ^ sw(row)));
        *(f16x8*)(vt + (bt * 64 + row) * 1024 + pos0 + c8 * 8) = val;
    }
}

// ---------------------------------------------------------------------------
// K2: channel attention, fp16 in -> fp16 cattn (rows already include softmax).
// ---------------------------------------------------------------------------
__global__ __launch_bounds__(256) void k_chan(const f16* __restrict__ q,
                                              const f16* __restrict__ k,
                                              f16* __restrict__ cattn) {
    __shared__ float qs[64][68];
    __shared__ float ks[64][68];
    __shared__ float sm[64][65];
    const int bt = blockIdx.x, tid = threadIdx.x;
    const int ti = tid >> 4, tj = tid & 15;
    float acc[4][4] = {{0.f}};

    for (int ch = 0; ch < 16; ++ch) {
        int p0 = ch * 64;
        __syncthreads();
        for (int it = 0; it < 2; ++it) {
            int e8 = it * 256 + tid;            // 512 octets of 8 f16
            int p = e8 >> 3, c8 = e8 & 7;
            f16x8 qv = *(const f16x8*)(q + (bt * 1024 + p0 + p) * 64 + c8 * 8);
            f16x8 kv = *(const f16x8*)(k + (bt * 1024 + p0 + p) * 64 + c8 * 8);
            float4 qlo = make_float4((float)qv[0], (float)qv[1], (float)qv[2], (float)qv[3]);
            float4 qhi = make_float4((float)qv[4], (float)qv[5], (float)qv[6], (float)qv[7]);
            float4 klo = make_float4((float)kv[0], (float)kv[1], (float)kv[2], (float)kv[3]);
            float4 khi = make_float4((float)kv[4], (float)kv[5], (float)kv[6], (float)kv[7]);
            *(float4*)&qs[p][c8 * 8]     = qlo;
            *(float4*)&qs[p][c8 * 8 + 4] = qhi;
            *(float4*)&ks[p][c8 * 8]     = klo;
            *(float4*)&ks[p][c8 * 8 + 4] = khi;
        }
        __syncthreads();
#pragma unroll 8
        for (int p = 0; p < 64; ++p) {
            float qa[4], ka[4];
            *(float4*)qa = *(const float4*)&qs[p][ti * 4];
            *(float4*)ka = *(const float4*)&ks[p][tj * 4];
#pragma unroll
            for (int r = 0; r < 4; ++r)
#pragma unroll
                for (int c = 0; c < 4; ++c)
                    acc[r][c] = fmaf(qa[r], ka[c], acc[r][c]);
        }
    }
#pragma unroll
    for (int r = 0; r < 4; ++r)
#pragma unroll
        for (int c = 0; c < 4; ++c)
            sm[ti * 4 + r][tj * 4 + c] = acc[r][c];
    __syncthreads();
    if (tid < 64) {
        float m = -1e30f;
        for (int j = 0; j < 64; ++j) m = fmaxf(m, sm[tid][j]);
        float s = 0.f;
        for (int j = 0; j < 64; ++j) { float e = __expf(sm[tid][j] - m); sm[tid][j] = e; s += e; }
        float inv = 1.f / s;
        for (int j = 0; j < 64; ++j) cattn[(bt * 64 + tid) * 64 + j] = (f16)(sm[tid][j] * inv);
    }
}

// ---------------------------------------------------------------------------
// K3: pixel flash attention + channel-out, fp16 MFMA, 128 rows/block.
// grid (bt=64, rowtile=8): wgid%8 = bt%8 -> all blocks of one bt share an XCD.
// Writes xhat as SPLIT fp16 (hi + lo), token-major [bt][pos][c].
// ---------------------------------------------------------------------------
__global__ __launch_bounds__(256) void k_pixel(const f16* __restrict__ q,
                                               const f16* __restrict__ k,
                                               const f16* __restrict__ v,
                                               const f16* __restrict__ vt,
                                               const f16* __restrict__ cattn,
                                               f16* __restrict__ xh,
                                               f16* __restrict__ xl) {
    __shared__ f16 q_s[8192];   // [row<128][c] swizzled
    __shared__ f16 k_s[4096];   // [j<64][c] swizzled
    __shared__ f16 vt_s[4096];  // [c<64][j] swizzled (from pre-transposed vt)
    __shared__ f16 p_s[8192];   // [row<128][j] swizzled

    const int bt = blockIdx.x, row0 = blockIdx.y * 128;
    const int tid = threadIdx.x;
    const int wv = tid >> 6;          // wave id
    const int ln = tid & 15;          // lane&15
    const int kgrp = (tid >> 4) & 3;  // lane>>4

    // ---- stage Q tile (128 rows) ----
    {
        const f16* qg = q + (bt * 1024 + row0) * 64;
#pragma unroll
        for (int p = 0; p < 4; ++p) {
            int e8 = p * 256 + tid;
            int r2 = e8 >> 3, c8 = e8 & 7;
            f16x8 val = *(const f16x8*)(qg + r2 * 64 + c8 * 8);
            *(f16x8*)((char*)q_s + r2 * 128 + ((c8 * 16) ^ sw(r2))) = val;
        }
    }

    f32x4 out[2][4];
    float lr[2][4];
#pragma unroll
    for (int rt = 0; rt < 2; ++rt)
#pragma unroll
        for (int ct = 0; ct < 4; ++ct) {
            out[rt][ct] = (f32x4){0.f, 0.f, 0.f, 0.f};
            lr[rt][ct] = 0.f;
        }

    for (int ch = 0; ch < 16; ++ch) {
        const int j0 = ch * 64;
        __syncthreads();   // prior chunk's reads of k_s/vt_s/p_s done
        {
            const f16* kg = k + (bt * 1024 + j0) * 64;
            const f16* vtg = vt + (size_t)bt * 65536 + j0;
#pragma unroll
            for (int p = 0; p < 2; ++p) {
                int e8 = p * 256 + tid;
                int r2 = e8 >> 3, c8 = e8 & 7;
                f16x8 kv = *(const f16x8*)(kg + r2 * 64 + c8 * 8);
                *(f16x8*)((char*)k_s + r2 * 128 + ((c8 * 16) ^ sw(r2))) = kv;
                f16x8 tv = *(const f16x8*)(vtg + r2 * 1024 + c8 * 8);   // row r2 = channel
                *(f16x8*)((char*)vt_s + r2 * 128 + ((c8 * 16) ^ sw(r2))) = tv;
            }
        }
        __syncthreads();

        // ---- K fragments (shared across row-tiles) ----
        f16x8 kf[4][2];
#pragma unroll
        for (int jt = 0; jt < 4; ++jt)
#pragma unroll
            for (int kb = 0; kb < 2; ++kb) {
                int jr = jt * 16 + ln;
                kf[jt][kb] = *(const f16x8*)((char*)k_s + jr * 128 + (((kb * 4 + kgrp) * 16) ^ sw(jr)));
            }

        // ---- S = Q K^T + exp + P store, per row-tile ----
#pragma unroll
        for (int rt = 0; rt < 2; ++rt) {
            int rr = rt * 64 + 16 * wv + ln;
            f16x8 qa[2];
#pragma unroll
            for (int kb = 0; kb < 2; ++kb)
                qa[kb] = *(const f16x8*)((char*)q_s + rr * 128 + (((kb * 4 + kgrp) * 16) ^ sw(rr)));
            f32x4 sx[4];
#pragma unroll
            for (int jt = 0; jt < 4; ++jt) sx[jt] = (f32x4){0.f, 0.f, 0.f, 0.f};
#pragma unroll
            for (int jt = 0; jt < 4; ++jt)
#pragma unroll
                for (int kb = 0; kb < 2; ++kb)
                    sx[jt] = MFMA16(qa[kb], kf[jt][kb], sx[jt]);
#pragma unroll
            for (int jt = 0; jt < 4; ++jt)
#pragma unroll
                for (int r = 0; r < 4; ++r) {
                    float p = __expf(sx[jt][r]);
                    lr[rt][r] += p;
                    int prow = rt * 64 + 16 * wv + kgrp * 4 + r;
                    int pcol = jt * 16 + ln;
                    *(f16*)((char*)p_s + prow * 128 + ((pcol * 2) ^ sw(prow))) = (f16)p;
                }
        }
        __syncthreads();

        // ---- V fragments (shared across row-tiles) ----
        f16x8 vf[4][2];
#pragma unroll
        for (int ct = 0; ct < 4; ++ct)
#pragma unroll
            for (int kb = 0; kb < 2; ++kb) {
                int cr = ct * 16 + ln;
                vf[ct][kb] = *(const f16x8*)((char*)vt_s + cr * 128 + (((kb * 4 + kgrp) * 16) ^ sw(cr)));
            }
        // ---- out += P V ----
#pragma unroll
        for (int rt = 0; rt < 2; ++rt) {
            int rr = rt * 64 + 16 * wv + ln;
            f16x8 pa[2];
#pragma unroll
            for (int kb = 0; kb < 2; ++kb)
                pa[kb] = *(const f16x8*)((char*)p_s + rr * 128 + (((kb * 4 + kgrp) * 16) ^ sw(rr)));
#pragma unroll
            for (int ct = 0; ct < 4; ++ct)
#pragma unroll
                for (int kb = 0; kb < 2; ++kb)
                    out[rt][ct] = MFMA16(pa[kb], vf[ct][kb], out[rt][ct]);
        }
    }

    // ---- finish pixel softmax: reduce row-sums over the 16 col-lanes ----
#pragma unroll
    for (int mask = 1; mask < 16; mask <<= 1)
#pragma unroll
        for (int rt = 0; rt < 2; ++rt)
#pragma unroll
            for (int r = 0; r < 4; ++r) lr[rt][r] += __shfl_xor(lr[rt][r], mask, 64);
#pragma unroll
    for (int rt = 0; rt < 2; ++rt)
#pragma unroll
        for (int r = 0; r < 4; ++r) {
            float inv = 1.f / lr[rt][r];
#pragma unroll
            for (int ct = 0; ct < 4; ++ct) out[rt][ct][r] *= inv;
        }

    // ---- channel contribution: out[pos][i] += sum_jc v[pos][jc] * cattn[i][jc] ----
    __syncthreads();   // all PV reads done before restaging
    {
        const f16* cg = cattn + bt * 4096;
#pragma unroll
        for (int p = 0; p < 2; ++p) {
            int e8 = p * 256 + tid;
            int r2 = e8 >> 3, c8 = e8 & 7;
            f16x8 cv = *(const f16x8*)(cg + r2 * 64 + c8 * 8);
            *(f16x8*)((char*)k_s + r2 * 128 + ((c8 * 16) ^ sw(r2))) = cv;
        }
        const f16* vg = v + (bt * 1024 + row0) * 64;
#pragma unroll
        for (int p = 0; p < 4; ++p) {
            int e8 = p * 256 + tid;
            int r2 = e8 >> 3, c8 = e8 & 7;
            f16x8 vv = *(const f16x8*)(vg + r2 * 64 + c8 * 8);
            *(f16x8*)((char*)q_s + r2 * 128 + ((c8 * 16) ^ sw(r2))) = vv;
        }
    }
    __syncthreads();
    {
        f16x8 cb[4][2];
#pragma unroll
        for (int it = 0; it < 4; ++it)
#pragma unroll
            for (int kb = 0; kb < 2; ++kb) {
                int ir = it * 16 + ln;
                cb[it][kb] = *(const f16x8*)((char*)k_s + ir * 128 + (((kb * 4 + kgrp) * 16) ^ sw(ir)));
            }
#pragma unroll
        for (int rt = 0; rt < 2; ++rt) {
            int rr = rt * 64 + 16 * wv + ln;
            f16x8 va[2];
#pragma unroll
            for (int kb = 0; kb < 2; ++kb)
                va[kb] = *(const f16x8*)((char*)q_s + rr * 128 + (((kb * 4 + kgrp) * 16) ^ sw(rr)));
#pragma unroll
            for (int it = 0; it < 4; ++it)
#pragma unroll
                for (int kb = 0; kb < 2; ++kb)
                    out[rt][it] = MFMA16(va[kb], cb[it][kb], out[rt][it]);
        }
    }

    // ---- store xhat as split fp16: hi + residual lo ----
#pragma unroll
    for (int rt = 0; rt < 2; ++rt)
#pragma unroll
        for (int ct = 0; ct < 4; ++ct)
#pragma unroll
            for (int r = 0; r < 4; ++r) {
                float val = out[rt][ct][r];
                f16 h = (f16)val;
                int idx = (bt * 1024 + row0 + rt * 64 + 16 * wv + kgrp * 4 + r) * 64 + ct * 16 + ln;
                xh[idx] = h;
                xl[idx] = (f16)(val - (float)h);
            }
}

// ---------------------------------------------------------------------------
// K4: temporal conv (3,1,1) pad (1,0,0) as split-fp16 MFMA GEMM:
//   C[pos 64][oc 128] = X[pos][cidt 192] * W^T, per (b,t,pos-tile)
//   C = Ah*Bh + Al*Bh + Ah*Bl  (22-bit effective mantissa, f32 accumulate)
// ---------------------------------------------------------------------------
__global__ __launch_bounds__(256) void k_tconv(const f16* __restrict__ xh,
                                               const f16* __restrict__ xl,
                                               const float* __restrict__ w,
                                               const float* __restrict__ bias,
                                               float* __restrict__ tq,
                                               float* __restrict__ tk) {
    __shared__ f16 xs[2][3][4096];   // [hiLo][dt][row*64+ci] swizzled rows, 48KB
    const int bt = blockIdx.y, pos0 = blockIdx.x * 64;
    const int b = bt >> 3, t = bt & 7;
    const int tid = threadIdx.x;
    const int wvid = tid >> 6, ln = tid & 15, kgrp = (tid >> 4) & 3;

    // ---- stage xhat hi/lo tiles for dt = 0..2 (zero-fill at temporal edges) ----
    for (int dt = 0; dt < 3; ++dt) {
        int tt = t + dt - 1;
        bool ok = (tt >= 0) && (tt < 8);
        const f16* srch = xh + ((b * 8 + tt) * 1024 + pos0) * 64;
        const f16* srcl = xl + ((b * 8 + tt) * 1024 + pos0) * 64;
#pragma unroll
        for (int p = 0; p < 2; ++p) {
            int e8 = p * 256 + tid;
            int r2 = e8 >> 3, c8 = e8 & 7;
            f16x8 vh = {0, 0, 0, 0, 0, 0, 0, 0};
            f16x8 vl = {0, 0, 0, 0, 0, 0, 0, 0};
            if (ok) {
                vh = *(const f16x8*)(srch + r2 * 64 + c8 * 8);
                vl = *(const f16x8*)(srcl + r2 * 64 + c8 * 8);
            }
            int byte = r2 * 128 + ((c8 * 16) ^ sw(r2));
            *(f16x8*)((char*)&xs[0][dt][0] + byte) = vh;
            *(f16x8*)((char*)&xs[1][dt][0] + byte) = vl;
        }
    }

    // ---- load W fragments (one-time): wave covers ocs wvid*32 .. wvid*32+31 ----
    f16x8 bh[2][6], bl[2][6];
#pragma unroll
    for (int og = 0; og < 2; ++og) {
        int oc = wvid * 32 + og * 16 + ln;    // 0..127 (0-63 -> tq, 64-127 -> tk)
#pragma unroll
        for (int kc = 0; kc < 6; ++kc) {
            f16x8 hbuf, lbuf;
#pragma unroll
            for (int j = 0; j < 8; ++j) {
                int K = kc * 32 + kgrp * 8 + j;
                int dt = K >> 6, ci = K & 63;
                float wf = w[(oc * 64 + ci) * 3 + dt];
                f16 h = (f16)wf;
                hbuf[j] = h;
                lbuf[j] = (f16)(wf - (float)h);
            }
            bh[og][kc] = hbuf;
            bl[og][kc] = lbuf;
        }
    }
    __syncthreads();

    // ---- 4 pos-groups of 16; per group: load A frags, 2 oc-groups x 18 MFMA ----
#pragma unroll
    for (int pg = 0; pg < 4; ++pg) {
        f16x8 ah[6], al[6];
        int rr = pg * 16 + ln;
#pragma unroll
        for (int kc = 0; kc < 6; ++kc) {
            int dt = kc >> 1;
            int ci0 = (kc & 1) * 32 + kgrp * 8;
            int byte = rr * 128 + ((ci0 * 2) ^ sw(rr));
            ah[kc] = *(const f16x8*)((char*)&xs[0][dt][0] + byte);
            al[kc] = *(const f16x8*)((char*)&xs[1][dt][0] + byte);
        }
#pragma unroll
        for (int og = 0; og < 2; ++og) {
            int oc = wvid * 32 + og * 16 + ln;   // C col = ln -> same oc as B frag
            float bv = bias[oc];
            f32x4 acc = {bv, bv, bv, bv};
#pragma unroll
            for (int kc = 0; kc < 6; ++kc) {
                acc = MFMA16(ah[kc], bh[og][kc], acc);
                acc = MFMA16(al[kc], bh[og][kc], acc);
                acc = MFMA16(ah[kc], bl[og][kc], acc);
            }
            float* dst = (oc < 64) ? tq : tk;
            int orow = oc & 63;
            int pos = pos0 + pg * 16 + kgrp * 4;
            *(float4*)&dst[(bt * 64 + orow) * 1024 + pos] =
                make_float4(acc[0], acc[1], acc[2], acc[3]);
        }
    }
}

// ---------------------------------------------------------------------------
// K5: temporal dots partials: grid (128 d-chunks of 512, 8 b)
// ---------------------------------------------------------------------------
__global__ __launch_bounds__(256) void k_tdots(const float* __restrict__ tq,
                                               const float* __restrict__ tk,
                                               float* __restrict__ partials) {
    __shared__ float qs[8][516];
    __shared__ float ks[8][516];
    const int ch = blockIdx.x, b = blockIdx.y;
    const int tid = threadIdx.x;
    const int d0 = ch * 512;

    for (int it = 0; it < 4; ++it) {
        int f4 = it * 256 + tid;        // 1024 float4 per tensor
        int i = f4 >> 7, d4 = f4 & 127;
        *(float4*)&qs[i][d4 * 4] = *(const float4*)(tq + (size_t)(b * 8 + i) * 65536 + d0 + d4 * 4);
        *(float4*)&ks[i][d4 * 4] = *(const float4*)(tk + (size_t)(b * 8 + i) * 65536 + d0 + d4 * 4);
    }
    __syncthreads();

    const int p = tid >> 2, sub = tid & 3;
    const int i = p >> 3, j = p & 7;
    float acc = 0.f;
#pragma unroll 8
    for (int d4 = 0; d4 < 32; ++d4) {
        int off = (d4 * 4 + sub) * 4;
        float qa[4], ka[4];
        *(float4*)qa = *(const float4*)&qs[i][off];
        *(float4*)ka = *(const float4*)&ks[j][off];
        acc = dp4(qa, ka, acc);
    }
    acc += __shfl_xor(acc, 1, 64);
    acc += __shfl_xor(acc, 2, 64);
    if (sub == 0) partials[(b * 128 + ch) * 64 + p] = acc;
}

// K6: reduce partials + softmax over j. grid 8, 64 threads: thread = i*8+j.
__global__ void k_tsm(const float* __restrict__ partials, float* __restrict__ ta) {
    const int b = blockIdx.x, tid = threadIdx.x;
    float s = 0.f;
    for (int ch = 0; ch < 128; ++ch) s += partials[(b * 128 + ch) * 64 + tid];
    float m = s;
#pragma unroll
    for (int mask = 1; mask < 8; mask <<= 1) m = fmaxf(m, __shfl_xor(m, mask, 64));
    float e = __expf(s - m);
    float sum = e;
#pragma unroll
    for (int mask = 1; mask < 8; mask <<= 1) sum += __shfl_xor(sum, mask, 64);
    ta[b * 64 + tid] = e / sum;
}

// ---------------------------------------------------------------------------
// K7: out[b*8+kk][cc][pos] = sum_t ta[b][kk][t] * v[(b*8+t)][pos][cc]  (v fp16)
// ---------------------------------------------------------------------------
__global__ __launch_bounds__(256) void k_tout(const f16* __restrict__ v,
                                              const float* __restrict__ ta,
                                              float* __restrict__ outp) {
    __shared__ float ot[64][65];
    const int pt = blockIdx.x, kk = blockIdx.y, b = blockIdx.z;
    const int pos0 = pt * 64;
    const int tid = threadIdx.x;
    const int cc = tid & 63, grp = tid >> 6;
    float a[8];
#pragma unroll
    for (int t = 0; t < 8; ++t) a[t] = ta[(b * 8 + kk) * 8 + t];
    float acc[16] = {0.f};
#pragma unroll
    for (int t = 0; t < 8; ++t) {
        const f16* vb = v + ((size_t)(b * 8 + t) * 1024 + pos0) * 64 + cc;
#pragma unroll
        for (int pp = 0; pp < 16; ++pp)
            acc[pp] = fmaf(a[t], (float)vb[(grp * 16 + pp) * 64], acc[pp]);
    }
#pragma unroll
    for (int pp = 0; pp < 16; ++pp) ot[cc][grp * 16 + pp] = acc[pp];
    __syncthreads();
    for (int it = 0; it < 16; ++it) {
        int idx = it * 256 + tid;
        int c2 = idx >> 6, p2 = idx & 63;
        outp[((b * 8 + kk) * 64 + c2) * 1024 + pos0 + p2] = ot[c2][p2];
    }
}

// ---------------------------------------------------------------------------
extern "C" void kernel_launch(void* const* d_in, const int* in_sizes, int n_in,
                              void* d_out, int out_size, void* d_ws, size_t ws_size,
                              hipStream_t stream) {
    const float* x     = (const float*)d_in[0];
    const float* qkv_w = (const float*)d_in[1];
    const float* qkv_b = (const float*)d_in[2];
    const float* tqk_w = (const float*)d_in[3];
    const float* tqk_b = (const float*)d_in[4];
    float* outp = (float*)d_out;

    // ws layout (bytes):
    // [0,8M)   q fp16        -> later overlaid by tq f32 [0,16M)
    // [8M,16M) k fp16
    // [16M,24M) v fp16       (live until k_tout)
    // [24M,24.5M) cattn fp16
    // [24.5M,24.75M) partials f32 (256KB)
    // [24.75M,+2KB) ta f32
    // [25M,33M) xhat_hi fp16
    // [33M,41M) xhat_lo fp16
    // [41M,57M) tk f32
    // [57M,65M) vt fp16 (transposed v, live until k_pixel)
    char* wsb = (char*)d_ws;
    f16*   q        = (f16*)wsb;
    f16*   k        = (f16*)(wsb + (8u << 20));
    f16*   v        = (f16*)(wsb + (16u << 20));
    f16*   cattn    = (f16*)(wsb + (24u << 20));
    float* partials = (float*)(wsb + (24u << 20) + (1u << 19));
    float* ta       = (float*)(wsb + (24u << 20) + (1u << 19) + (1u << 18));
    f16*   xhat_hi  = (f16*)(wsb + (25u << 20));
    f16*   xhat_lo  = (f16*)(wsb + (33u << 20));
    float* tq       = (float*)wsb;                 // overlays q,k (dead after k_pixel)
    float* tk       = (float*)(wsb + (41u << 20));
    f16*   vt       = (f16*)(wsb + (57u << 20));

    k_qkv  <<<dim3(16, 64), 256, 0, stream>>>(x, qkv_w, qkv_b, q, k, v, vt);
    k_chan <<<dim3(64),     256, 0, stream>>>(q, k, cattn);
    k_pixel<<<dim3(64, 8),  256, 0, stream>>>(q, k, v, vt, cattn, xhat_hi, xhat_lo);
    k_tconv<<<dim3(16, 64), 256, 0, stream>>>(xhat_hi, xhat_lo, tqk_w, tqk_b, tq, tk);
    k_tdots<<<dim3(128, 8), 256, 0, stream>>>(tq, tk, partials);
    k_tsm  <<<dim3(8), 64, 0, stream>>>(partials, ta);
    k_tout <<<dim3(16, 8, 8), 256, 0, stream>>>(v, ta, outp);
}

// Round 6
// 183.698 us; speedup vs baseline: 3.5332x; 1.2601x over previous
//
#include <hip/hip_runtime.h>

// Problem constants: bt=64, c=64, h=w=32 -> n=1024, t=8, b=8.
#define SCALE 0.125f   // c^-0.5

typedef _Float16 f16;
typedef _Float16 f16x8 __attribute__((ext_vector_type(8)));
typedef float f32x4 __attribute__((ext_vector_type(4)));

#define MFMA16(A,B,C) __builtin_amdgcn_mfma_f32_16x16x32_f16(A,B,C,0,0,0)

__device__ __forceinline__ float dp4(const float a[4], const float b[4], float acc) {
    acc = fmaf(a[0], b[0], acc);
    acc = fmaf(a[1], b[1], acc);
    acc = fmaf(a[2], b[2], acc);
    acc = fmaf(a[3], b[3], acc);
    return acc;
}

// XOR swizzle for row-major 128B-row f16 tiles: toggles 16B slot.
__device__ __forceinline__ int sw(int row) {
    return ((row & 7) ^ ((row >> 3) & 7)) << 4;
}

// ---------------------------------------------------------------------------
// K1: qkv = W[192,64] @ x + b -> q (pre-scaled), k, v fp16 token-major [bt][pos][c]
//     + vt fp16 channel-major [bt][c][pos]
// ---------------------------------------------------------------------------
__global__ __launch_bounds__(256) void k_qkv(const float* __restrict__ x,
                                             const float* __restrict__ w,
                                             const float* __restrict__ bias,
                                             f16* __restrict__ q,
                                             f16* __restrict__ k,
                                             f16* __restrict__ v,
                                             f16* __restrict__ vt) {
    __shared__ float xs[64][64];
    __shared__ float ws[192][65];
    __shared__ f16 vts[4096];        // [oc][pos] swizzled 128B rows
    const int bt = blockIdx.y, pos0 = blockIdx.x * 64;
    const int tid = threadIdx.x;

    for (int it = 0; it < 16; ++it) {
        int idx = it * 256 + tid;
        int ci = idx >> 6, p = idx & 63;
        xs[ci][p] = x[(bt * 64 + ci) * 1024 + pos0 + p];
    }
    for (int it = 0; it < 48; ++it) {
        int idx = it * 256 + tid;
        ws[idx / 64][idx % 64] = w[idx];
    }
    __syncthreads();

    const int oc = tid & 63, grp = tid >> 6;
    float accq[16], acck[16], accv[16];
    const float bq = bias[oc], bk = bias[64 + oc], bv = bias[128 + oc];
#pragma unroll
    for (int p = 0; p < 16; ++p) { accq[p] = bq; acck[p] = bk; accv[p] = bv; }

    for (int ci = 0; ci < 64; ++ci) {
        float wq = ws[oc][ci], wk = ws[64 + oc][ci], wv = ws[128 + oc][ci];
        const float4* xr = (const float4*)&xs[ci][grp * 16];
#pragma unroll
        for (int p4 = 0; p4 < 4; ++p4) {
            float xa[4];
            *(float4*)xa = xr[p4];
#pragma unroll
            for (int e = 0; e < 4; ++e) {
                int p = p4 * 4 + e;
                accq[p] = fmaf(wq, xa[e], accq[p]);
                acck[p] = fmaf(wk, xa[e], acck[p]);
                accv[p] = fmaf(wv, xa[e], accv[p]);
            }
        }
    }
#pragma unroll
    for (int p = 0; p < 16; ++p) {
        int pos = pos0 + grp * 16 + p;
        int base = (bt * 1024 + pos) * 64 + oc;
        f16 vh = (f16)accv[p];
        q[base] = (f16)(accq[p] * SCALE);
        k[base] = (f16)acck[p];
        v[base] = vh;
        int col = grp * 16 + p;
        *(f16*)((char*)vts + oc * 128 + ((col * 2) ^ sw(oc))) = vh;
    }
    __syncthreads();
#pragma unroll
    for (int it = 0; it < 2; ++it) {
        int s = it * 256 + tid;
        int row = s >> 3, c8 = s & 7;
        f16x8 val = *(const f16x8*)((char*)vts + row * 128 + ((c8 * 16) ^ sw(row)));
        *(f16x8*)(vt + (bt * 64 + row) * 1024 + pos0 + c8 * 8) = val;
    }
}

// ---------------------------------------------------------------------------
// K2a: channel-attention partial dots over 256-pos chunks. grid (pc=4, bt=64).
// partials[bt][pc][i][j] = sum_{pos in chunk} q[pos][i] * k[pos][j]
// ---------------------------------------------------------------------------
__global__ __launch_bounds__(256) void k_chan_part(const f16* __restrict__ q,
                                                   const f16* __restrict__ k,
                                                   float* __restrict__ partials) {
    __shared__ float qs[64][68];
    __shared__ float ks[64][68];
    const int pc = blockIdx.x, bt = blockIdx.y, tid = threadIdx.x;
    const int ti = tid >> 4, tj = tid & 15;
    float acc[4][4] = {{0.f}};

    for (int ch = 0; ch < 4; ++ch) {
        int p0 = pc * 256 + ch * 64;
        __syncthreads();
        for (int it = 0; it < 2; ++it) {
            int e8 = it * 256 + tid;
            int p = e8 >> 3, c8 = e8 & 7;
            f16x8 qv = *(const f16x8*)(q + (bt * 1024 + p0 + p) * 64 + c8 * 8);
            f16x8 kv = *(const f16x8*)(k + (bt * 1024 + p0 + p) * 64 + c8 * 8);
            float4 qlo = make_float4((float)qv[0], (float)qv[1], (float)qv[2], (float)qv[3]);
            float4 qhi = make_float4((float)qv[4], (float)qv[5], (float)qv[6], (float)qv[7]);
            float4 klo = make_float4((float)kv[0], (float)kv[1], (float)kv[2], (float)kv[3]);
            float4 khi = make_float4((float)kv[4], (float)kv[5], (float)kv[6], (float)kv[7]);
            *(float4*)&qs[p][c8 * 8]     = qlo;
            *(float4*)&qs[p][c8 * 8 + 4] = qhi;
            *(float4*)&ks[p][c8 * 8]     = klo;
            *(float4*)&ks[p][c8 * 8 + 4] = khi;
        }
        __syncthreads();
#pragma unroll 8
        for (int p = 0; p < 64; ++p) {
            float qa[4], ka[4];
            *(float4*)qa = *(const float4*)&qs[p][ti * 4];
            *(float4*)ka = *(const float4*)&ks[p][tj * 4];
#pragma unroll
            for (int r = 0; r < 4; ++r)
#pragma unroll
                for (int c = 0; c < 4; ++c)
                    acc[r][c] = fmaf(qa[r], ka[c], acc[r][c]);
        }
    }
#pragma unroll
    for (int r = 0; r < 4; ++r) {
        float4 o4 = make_float4(acc[r][0], acc[r][1], acc[r][2], acc[r][3]);
        *(float4*)&partials[((bt * 4 + pc) * 64 + ti * 4 + r) * 64 + tj * 4] = o4;
    }
}

// K2b: reduce partials + row softmax -> cattn fp16. grid 64 (bt), 256 thr.
// thread: row i = tid>>2, j-quarter q4 = tid&3 (16 j each).
__global__ __launch_bounds__(256) void k_chan_red(const float* __restrict__ partials,
                                                  f16* __restrict__ cattn) {
    const int bt = blockIdx.x, tid = threadIdx.x;
    const int i = tid >> 2, q4 = tid & 3;
    float s[16];
#pragma unroll
    for (int jj = 0; jj < 16; ++jj) s[jj] = 0.f;
#pragma unroll
    for (int pc = 0; pc < 4; ++pc) {
        const float4* src = (const float4*)(partials + ((bt * 4 + pc) * 64 + i) * 64 + q4 * 16);
#pragma unroll
        for (int f4 = 0; f4 < 4; ++f4) {
            float a[4];
            *(float4*)a = src[f4];
#pragma unroll
            for (int e = 0; e < 4; ++e) s[f4 * 4 + e] += a[e];
        }
    }
    float m = -1e30f;
#pragma unroll
    for (int jj = 0; jj < 16; ++jj) m = fmaxf(m, s[jj]);
    m = fmaxf(m, __shfl_xor(m, 1, 64));
    m = fmaxf(m, __shfl_xor(m, 2, 64));
    float e[16], sum = 0.f;
#pragma unroll
    for (int jj = 0; jj < 16; ++jj) { e[jj] = __expf(s[jj] - m); sum += e[jj]; }
    sum += __shfl_xor(sum, 1, 64);
    sum += __shfl_xor(sum, 2, 64);
    float inv = 1.f / sum;
    f16x8 o0, o1;
#pragma unroll
    for (int jj = 0; jj < 8; ++jj) { o0[jj] = (f16)(e[jj] * inv); o1[jj] = (f16)(e[8 + jj] * inv); }
    f16* dst = cattn + (bt * 64 + i) * 64 + q4 * 16;
    *(f16x8*)dst = o0;
    *(f16x8*)(dst + 8) = o1;
}

// ---------------------------------------------------------------------------
// K3: pixel flash attention + channel-out. 128 rows/block, fp16 MFMA.
// Q frags in registers; K/vt double-buffered with reg-prefetch; ONE barrier
// per chunk (P round-trip is wave-private -> no barrier needed).
// ---------------------------------------------------------------------------
__global__ __launch_bounds__(256) void k_pixel(const f16* __restrict__ q,
                                               const f16* __restrict__ k,
                                               const f16* __restrict__ v,
                                               const f16* __restrict__ vt,
                                               const f16* __restrict__ cattn,
                                               f16* __restrict__ xh,
                                               f16* __restrict__ xl) {
    __shared__ f16 kv_s[2][8192];   // [buf][ k_s: 0..4095 | vt_s: 4096..8191 ]
    __shared__ f16 p_s[8192];       // Q staging (prologue) -> P tiles -> v-tile (epilogue)

    const int bt = blockIdx.x, row0 = blockIdx.y * 128;
    const int tid = threadIdx.x;
    const int wv = tid >> 6;
    const int ln = tid & 15;
    const int kgrp = (tid >> 4) & 3;
    const int r2 = tid >> 3, c8 = tid & 7;   // staging coords (64 rows per 512 e8)

    f16x8 k0, k1, v0, v1;   // prefetch registers
    const f16* kbase = k + bt * 1024 * 64;
    const f16* vtbase = vt + (size_t)bt * 65536;

    auto issue = [&](int ch) {
        const f16* kg = kbase + ch * 64 * 64;
        const f16* vtg = vtbase + ch * 64;
        k0 = *(const f16x8*)(kg + r2 * 64 + c8 * 8);
        k1 = *(const f16x8*)(kg + (r2 + 32) * 64 + c8 * 8);
        v0 = *(const f16x8*)(vtg + r2 * 1024 + c8 * 8);
        v1 = *(const f16x8*)(vtg + (r2 + 32) * 1024 + c8 * 8);
    };
    auto commit = [&](int buf) {
        char* kb = (char*)&kv_s[buf][0];
        char* vb = (char*)&kv_s[buf][4096];
        *(f16x8*)(kb + r2 * 128 + ((c8 * 16) ^ sw(r2))) = k0;
        *(f16x8*)(kb + (r2 + 32) * 128 + ((c8 * 16) ^ sw(r2 + 32))) = k1;
        *(f16x8*)(vb + r2 * 128 + ((c8 * 16) ^ sw(r2))) = v0;
        *(f16x8*)(vb + (r2 + 32) * 128 + ((c8 * 16) ^ sw(r2 + 32))) = v1;
    };

    // ---- prologue: issue ch0, stage Q into p_s, read Q frags, commit ch0, issue ch1
    issue(0);
    {
        const f16* qg = q + (bt * 1024 + row0) * 64;
#pragma unroll
        for (int p = 0; p < 4; ++p) {
            int e8 = p * 256 + tid;
            int rr = e8 >> 3, cc = e8 & 7;
            f16x8 val = *(const f16x8*)(qg + rr * 64 + cc * 8);
            *(f16x8*)((char*)p_s + rr * 128 + ((cc * 16) ^ sw(rr))) = val;
        }
    }
    __syncthreads();
    f16x8 qa[2][2];
#pragma unroll
    for (int rt = 0; rt < 2; ++rt) {
        int rr = rt * 64 + 16 * wv + ln;
#pragma unroll
        for (int kb = 0; kb < 2; ++kb)
            qa[rt][kb] = *(const f16x8*)((char*)p_s + rr * 128 + (((kb * 4 + kgrp) * 16) ^ sw(rr)));
    }
    commit(0);
    issue(1);
    __syncthreads();

    f32x4 out[2][4];
    float lr[2][4];
#pragma unroll
    for (int rt = 0; rt < 2; ++rt)
#pragma unroll
        for (int ct = 0; ct < 4; ++ct) {
            out[rt][ct] = (f32x4){0.f, 0.f, 0.f, 0.f};
            lr[rt][ct] = 0.f;
        }

    for (int ch = 0; ch < 16; ++ch) {
        const char* kb = (const char*)&kv_s[ch & 1][0];
        const char* vb = (const char*)&kv_s[ch & 1][4096];

        // K fragments
        f16x8 kf[4][2];
#pragma unroll
        for (int jt = 0; jt < 4; ++jt)
#pragma unroll
            for (int kb2 = 0; kb2 < 2; ++kb2) {
                int jr = jt * 16 + ln;
                kf[jt][kb2] = *(const f16x8*)(kb + jr * 128 + (((kb2 * 4 + kgrp) * 16) ^ sw(jr)));
            }
        // S = Q K^T, exp, wave-private P store
#pragma unroll
        for (int rt = 0; rt < 2; ++rt) {
            f32x4 sx[4];
#pragma unroll
            for (int jt = 0; jt < 4; ++jt) sx[jt] = (f32x4){0.f, 0.f, 0.f, 0.f};
#pragma unroll
            for (int jt = 0; jt < 4; ++jt)
#pragma unroll
                for (int kb2 = 0; kb2 < 2; ++kb2)
                    sx[jt] = MFMA16(qa[rt][kb2], kf[jt][kb2], sx[jt]);
#pragma unroll
            for (int jt = 0; jt < 4; ++jt)
#pragma unroll
                for (int r = 0; r < 4; ++r) {
                    float p = __expf(sx[jt][r]);
                    lr[rt][r] += p;
                    int prow = rt * 64 + 16 * wv + kgrp * 4 + r;
                    int pcol = jt * 16 + ln;
                    *(f16*)((char*)p_s + prow * 128 + ((pcol * 2) ^ sw(prow))) = (f16)p;
                }
        }
        // V fragments
        f16x8 vf[4][2];
#pragma unroll
        for (int ct = 0; ct < 4; ++ct)
#pragma unroll
            for (int kb2 = 0; kb2 < 2; ++kb2) {
                int cr = ct * 16 + ln;
                vf[ct][kb2] = *(const f16x8*)(vb + cr * 128 + (((kb2 * 4 + kgrp) * 16) ^ sw(cr)));
            }
        // out += P V  (pa reads are wave-private rows of p_s; in-order LDS pipe)
#pragma unroll
        for (int rt = 0; rt < 2; ++rt) {
            int rr = rt * 64 + 16 * wv + ln;
            f16x8 pa[2];
#pragma unroll
            for (int kb2 = 0; kb2 < 2; ++kb2)
                pa[kb2] = *(const f16x8*)((char*)p_s + rr * 128 + (((kb2 * 4 + kgrp) * 16) ^ sw(rr)));
#pragma unroll
            for (int ct = 0; ct < 4; ++ct)
#pragma unroll
                for (int kb2 = 0; kb2 < 2; ++kb2)
                    out[rt][ct] = MFMA16(pa[kb2], vf[ct][kb2], out[rt][ct]);
        }
        // commit next chunk, issue the one after
        if (ch < 15) {
            commit((ch + 1) & 1);
            if (ch < 14) issue(ch + 2);
        }
        __syncthreads();
    }

    // ---- finish pixel softmax ----
#pragma unroll
    for (int mask = 1; mask < 16; mask <<= 1)
#pragma unroll
        for (int rt = 0; rt < 2; ++rt)
#pragma unroll
            for (int r = 0; r < 4; ++r) lr[rt][r] += __shfl_xor(lr[rt][r], mask, 64);
#pragma unroll
    for (int rt = 0; rt < 2; ++rt)
#pragma unroll
        for (int r = 0; r < 4; ++r) {
            float inv = 1.f / lr[rt][r];
#pragma unroll
            for (int ct = 0; ct < 4; ++ct) out[rt][ct][r] *= inv;
        }

    // ---- channel contribution ----
    {
        f16* cs = &kv_s[0][0];        // cattn 64 rows (8KB)
        const f16* cg = cattn + bt * 4096;
#pragma unroll
        for (int p = 0; p < 2; ++p) {
            int e8 = p * 256 + tid;
            int rr = e8 >> 3, cc = e8 & 7;
            f16x8 cv = *(const f16x8*)(cg + rr * 64 + cc * 8);
            *(f16x8*)((char*)cs + rr * 128 + ((cc * 16) ^ sw(rr))) = cv;
        }
        const f16* vg = v + (bt * 1024 + row0) * 64;
#pragma unroll
        for (int p = 0; p < 4; ++p) {
            int e8 = p * 256 + tid;
            int rr = e8 >> 3, cc = e8 & 7;
            f16x8 vv = *(const f16x8*)(vg + rr * 64 + cc * 8);
            *(f16x8*)((char*)p_s + rr * 128 + ((cc * 16) ^ sw(rr))) = vv;
        }
    }
    __syncthreads();
    {
        const char* cs = (const char*)&kv_s[0][0];
        f16x8 cb[4][2];
#pragma unroll
        for (int it = 0; it < 4; ++it)
#pragma unroll
            for (int kb2 = 0; kb2 < 2; ++kb2) {
                int ir = it * 16 + ln;
                cb[it][kb2] = *(const f16x8*)(cs + ir * 128 + (((kb2 * 4 + kgrp) * 16) ^ sw(ir)));
            }
#pragma unroll
        for (int rt = 0; rt < 2; ++rt) {
            int rr = rt * 64 + 16 * wv + ln;
            f16x8 va[2];
#pragma unroll
            for (int kb2 = 0; kb2 < 2; ++kb2)
                va[kb2] = *(const f16x8*)((char*)p_s + rr * 128 + (((kb2 * 4 + kgrp) * 16) ^ sw(rr)));
#pragma unroll
            for (int it = 0; it < 4; ++it)
#pragma unroll
                for (int kb2 = 0; kb2 < 2; ++kb2)
                    out[rt][it] = MFMA16(va[kb2], cb[it][kb2], out[rt][it]);
        }
    }

    // ---- store xhat as split fp16 ----
#pragma unroll
    for (int rt = 0; rt < 2; ++rt)
#pragma unroll
        for (int ct = 0; ct < 4; ++ct)
#pragma unroll
            for (int r = 0; r < 4; ++r) {
                float val = out[rt][ct][r];
                f16 h = (f16)val;
                int idx = (bt * 1024 + row0 + rt * 64 + 16 * wv + kgrp * 4 + r) * 64 + ct * 16 + ln;
                xh[idx] = h;
                xl[idx] = (f16)(val - (float)h);
            }
}

// ---------------------------------------------------------------------------
// K_wprep: split conv weights into fragment-ordered fp16 hi/lo.
// dest d in [0,24576): j=d&7, oc=(d>>3)&127, kgrp=(d>>10)&3, kc=d>>12.
// ---------------------------------------------------------------------------
__global__ void k_wprep(const float* __restrict__ w, f16* __restrict__ wsplit) {
    int d = blockIdx.x * 256 + threadIdx.x;
    int j = d & 7, oc = (d >> 3) & 127, kg = (d >> 10) & 3, kc = d >> 12;
    int K = kc * 32 + kg * 8 + j;
    int dt = K >> 6, ci = K & 63;
    float wf = w[(oc * 64 + ci) * 3 + dt];
    f16 h = (f16)wf;
    wsplit[d] = h;                   // hi
    wsplit[24576 + d] = (f16)(wf - (float)h);  // lo
}

// ---------------------------------------------------------------------------
// K4: temporal conv (3,1,1) as split-fp16 MFMA GEMM, weights from wsplit.
// ---------------------------------------------------------------------------
__global__ __launch_bounds__(256) void k_tconv(const f16* __restrict__ xh,
                                               const f16* __restrict__ xl,
                                               const f16* __restrict__ wsplit,
                                               const float* __restrict__ bias,
                                               float* __restrict__ tq,
                                               float* __restrict__ tk) {
    __shared__ f16 xs[2][3][4096];
    const int bt = blockIdx.y, pos0 = blockIdx.x * 64;
    const int b = bt >> 3, t = bt & 7;
    const int tid = threadIdx.x;
    const int wvid = tid >> 6, ln = tid & 15, kgrp = (tid >> 4) & 3;

    for (int dt = 0; dt < 3; ++dt) {
        int tt = t + dt - 1;
        bool ok = (tt >= 0) && (tt < 8);
        const f16* srch = xh + ((b * 8 + tt) * 1024 + pos0) * 64;
        const f16* srcl = xl + ((b * 8 + tt) * 1024 + pos0) * 64;
#pragma unroll
        for (int p = 0; p < 2; ++p) {
            int e8 = p * 256 + tid;
            int r2 = e8 >> 3, c8 = e8 & 7;
            f16x8 vh = {0, 0, 0, 0, 0, 0, 0, 0};
            f16x8 vl = {0, 0, 0, 0, 0, 0, 0, 0};
            if (ok) {
                vh = *(const f16x8*)(srch + r2 * 64 + c8 * 8);
                vl = *(const f16x8*)(srcl + r2 * 64 + c8 * 8);
            }
            int byte = r2 * 128 + ((c8 * 16) ^ sw(r2));
            *(f16x8*)((char*)&xs[0][dt][0] + byte) = vh;
            *(f16x8*)((char*)&xs[1][dt][0] + byte) = vl;
        }
    }

    // ---- W fragments: coalesced from wsplit ----
    f16x8 bh[2][6], bl[2][6];
#pragma unroll
    for (int og = 0; og < 2; ++og) {
        int oc = wvid * 32 + og * 16 + ln;
#pragma unroll
        for (int kc = 0; kc < 6; ++kc) {
            int idx = (kc * 4 + kgrp) * 1024 + oc * 8;
            bh[og][kc] = *(const f16x8*)(wsplit + idx);
            bl[og][kc] = *(const f16x8*)(wsplit + 24576 + idx);
        }
    }
    __syncthreads();

#pragma unroll
    for (int pg = 0; pg < 4; ++pg) {
        f16x8 ah[6], al[6];
        int rr = pg * 16 + ln;
#pragma unroll
        for (int kc = 0; kc < 6; ++kc) {
            int dt = kc >> 1;
            int ci0 = (kc & 1) * 32 + kgrp * 8;
            int byte = rr * 128 + ((ci0 * 2) ^ sw(rr));
            ah[kc] = *(const f16x8*)((char*)&xs[0][dt][0] + byte);
            al[kc] = *(const f16x8*)((char*)&xs[1][dt][0] + byte);
        }
#pragma unroll
        for (int og = 0; og < 2; ++og) {
            int oc = wvid * 32 + og * 16 + ln;
            float bv = bias[oc];
            f32x4 acc = {bv, bv, bv, bv};
#pragma unroll
            for (int kc = 0; kc < 6; ++kc) {
                acc = MFMA16(ah[kc], bh[og][kc], acc);
                acc = MFMA16(al[kc], bh[og][kc], acc);
                acc = MFMA16(ah[kc], bl[og][kc], acc);
            }
            float* dst = (oc < 64) ? tq : tk;
            int orow = oc & 63;
            int pos = pos0 + pg * 16 + kgrp * 4;
            *(float4*)&dst[(bt * 64 + orow) * 1024 + pos] =
                make_float4(acc[0], acc[1], acc[2], acc[3]);
        }
    }
}

// ---------------------------------------------------------------------------
// K5: temporal dots partials: grid (128 d-chunks of 512, 8 b)
// ---------------------------------------------------------------------------
__global__ __launch_bounds__(256) void k_tdots(const float* __restrict__ tq,
                                               const float* __restrict__ tk,
                                               float* __restrict__ partials) {
    __shared__ float qs[8][516];
    __shared__ float ks[8][516];
    const int ch = blockIdx.x, b = blockIdx.y;
    const int tid = threadIdx.x;
    const int d0 = ch * 512;

    for (int it = 0; it < 4; ++it) {
        int f4 = it * 256 + tid;
        int i = f4 >> 7, d4 = f4 & 127;
        *(float4*)&qs[i][d4 * 4] = *(const float4*)(tq + (size_t)(b * 8 + i) * 65536 + d0 + d4 * 4);
        *(float4*)&ks[i][d4 * 4] = *(const float4*)(tk + (size_t)(b * 8 + i) * 65536 + d0 + d4 * 4);
    }
    __syncthreads();

    const int p = tid >> 2, sub = tid & 3;
    const int i = p >> 3, j = p & 7;
    float acc = 0.f;
#pragma unroll 8
    for (int d4 = 0; d4 < 32; ++d4) {
        int off = (d4 * 4 + sub) * 4;
        float qa[4], ka[4];
        *(float4*)qa = *(const float4*)&qs[i][off];
        *(float4*)ka = *(const float4*)&ks[j][off];
        acc = dp4(qa, ka, acc);
    }
    acc += __shfl_xor(acc, 1, 64);
    acc += __shfl_xor(acc, 2, 64);
    if (sub == 0) partials[(b * 128 + ch) * 64 + p] = acc;
}

// K6: reduce partials + softmax over j. grid 8, 64 threads.
__global__ void k_tsm(const float* __restrict__ partials, float* __restrict__ ta) {
    const int b = blockIdx.x, tid = threadIdx.x;
    float s = 0.f;
    for (int ch = 0; ch < 128; ++ch) s += partials[(b * 128 + ch) * 64 + tid];
    float m = s;
#pragma unroll
    for (int mask = 1; mask < 8; mask <<= 1) m = fmaxf(m, __shfl_xor(m, mask, 64));
    float e = __expf(s - m);
    float sum = e;
#pragma unroll
    for (int mask = 1; mask < 8; mask <<= 1) sum += __shfl_xor(sum, mask, 64);
    ta[b * 64 + tid] = e / sum;
}

// ---------------------------------------------------------------------------
// K7: out[b*8+kk][cc][pos] = sum_t ta[b][kk][t] * v[(b*8+t)][pos][cc]
// ---------------------------------------------------------------------------
__global__ __launch_bounds__(256) void k_tout(const f16* __restrict__ v,
                                              const float* __restrict__ ta,
                                              float* __restrict__ outp) {
    __shared__ float ot[64][65];
    const int pt = blockIdx.x, kk = blockIdx.y, b = blockIdx.z;
    const int pos0 = pt * 64;
    const int tid = threadIdx.x;
    const int cc = tid & 63, grp = tid >> 6;
    float a[8];
#pragma unroll
    for (int t = 0; t < 8; ++t) a[t] = ta[(b * 8 + kk) * 8 + t];
    float acc[16] = {0.f};
#pragma unroll
    for (int t = 0; t < 8; ++t) {
        const f16* vb = v + ((size_t)(b * 8 + t) * 1024 + pos0) * 64 + cc;
#pragma unroll
        for (int pp = 0; pp < 16; ++pp)
            acc[pp] = fmaf(a[t], (float)vb[(grp * 16 + pp) * 64], acc[pp]);
    }
#pragma unroll
    for (int pp = 0; pp < 16; ++pp) ot[cc][grp * 16 + pp] = acc[pp];
    __syncthreads();
    for (int it = 0; it < 16; ++it) {
        int idx = it * 256 + tid;
        int c2 = idx >> 6, p2 = idx & 63;
        outp[((b * 8 + kk) * 64 + c2) * 1024 + pos0 + p2] = ot[c2][p2];
    }
}

// ---------------------------------------------------------------------------
extern "C" void kernel_launch(void* const* d_in, const int* in_sizes, int n_in,
                              void* d_out, int out_size, void* d_ws, size_t ws_size,
                              hipStream_t stream) {
    const float* x     = (const float*)d_in[0];
    const float* qkv_w = (const float*)d_in[1];
    const float* qkv_b = (const float*)d_in[2];
    const float* tqk_w = (const float*)d_in[3];
    const float* tqk_b = (const float*)d_in[4];
    float* outp = (float*)d_out;

    // ws layout (bytes):
    // [0,8M)    q fp16        -> later overlaid by tq f32 [0,16M)
    // [8M,16M)  k fp16
    // [16M,24M) v fp16        (live until k_tout)
    // [24M,24.5M)  cattn fp16
    // [24.5M,24.75M) tdots partials f32
    // [24.75M,+2KB)  ta f32
    // [24.75M+8K, +96KB) wsplit fp16 (hi 48K, lo 48K)
    // [25M,33M) xhat_hi fp16
    // [33M,41M) xhat_lo fp16
    // [41M,45M) chan partials f32 (dead before tk) -> tk f32 [41M,57M)
    // [57M,65M) vt fp16
    char* wsb = (char*)d_ws;
    f16*   q        = (f16*)wsb;
    f16*   k        = (f16*)(wsb + (8u << 20));
    f16*   v        = (f16*)(wsb + (16u << 20));
    f16*   cattn    = (f16*)(wsb + (24u << 20));
    float* tpart    = (float*)(wsb + (24u << 20) + (1u << 19));
    float* ta       = (float*)(wsb + (24u << 20) + (1u << 19) + (1u << 18));
    f16*   wsplit   = (f16*)(wsb + (24u << 20) + (1u << 19) + (1u << 18) + 8192);
    f16*   xhat_hi  = (f16*)(wsb + (25u << 20));
    f16*   xhat_lo  = (f16*)(wsb + (33u << 20));
    float* cpart    = (float*)(wsb + (41u << 20));
    float* tq       = (float*)wsb;
    float* tk       = (float*)(wsb + (41u << 20));
    f16*   vt       = (f16*)(wsb + (57u << 20));

    k_qkv      <<<dim3(16, 64), 256, 0, stream>>>(x, qkv_w, qkv_b, q, k, v, vt);
    k_wprep    <<<dim3(96), 256, 0, stream>>>(tqk_w, wsplit);
    k_chan_part<<<dim3(4, 64), 256, 0, stream>>>(q, k, cpart);
    k_chan_red <<<dim3(64), 256, 0, stream>>>(cpart, cattn);
    k_pixel    <<<dim3(64, 8), 256, 0, stream>>>(q, k, v, vt, cattn, xhat_hi, xhat_lo);
    k_tconv    <<<dim3(16, 64), 256, 0, stream>>>(xhat_hi, xhat_lo, wsplit, tqk_b, tq, tk);
    k_tdots    <<<dim3(128, 8), 256, 0, stream>>>(tq, tk, tpart);
    k_tsm      <<<dim3(8), 64, 0, stream>>>(tpart, ta);
    k_tout     <<<dim3(16, 8, 8), 256, 0, stream>>>(v, ta, outp);
}

// Round 7
// 178.317 us; speedup vs baseline: 3.6398x; 1.0302x over previous
//
#include <hip/hip_runtime.h>

// Problem constants: bt=64, c=64, h=w=32 -> n=1024, t=8, b=8.
#define SCALE 0.125f   // c^-0.5

typedef _Float16 f16;
typedef _Float16 f16x2 __attribute__((ext_vector_type(2)));
typedef _Float16 f16x8 __attribute__((ext_vector_type(8)));
typedef float f32x4 __attribute__((ext_vector_type(4)));

#define MFMA16(A,B,C) __builtin_amdgcn_mfma_f32_16x16x32_f16(A,B,C,0,0,0)

__device__ __forceinline__ float dp4(const float a[4], const float b[4], float acc) {
    acc = fmaf(a[0], b[0], acc);
    acc = fmaf(a[1], b[1], acc);
    acc = fmaf(a[2], b[2], acc);
    acc = fmaf(a[3], b[3], acc);
    return acc;
}

// XOR swizzle for row-major 128B-row f16 tiles: toggles 16B slot.
__device__ __forceinline__ int sw(int row) {
    return ((row & 7) ^ ((row >> 3) & 7)) << 4;
}

// ---------------------------------------------------------------------------
// K1: qkv GEMM -> q (pre-scaled), k, v fp16 token-major + vt channel-major.
// blockIdx.y == 64: conv-weight split prep (fused k_wprep).
// ---------------------------------------------------------------------------
__global__ __launch_bounds__(256) void k_qkv(const float* __restrict__ x,
                                             const float* __restrict__ w,
                                             const float* __restrict__ bias,
                                             const float* __restrict__ tqkw,
                                             f16* __restrict__ q,
                                             f16* __restrict__ k,
                                             f16* __restrict__ v,
                                             f16* __restrict__ vt,
                                             f16* __restrict__ wsplit) {
    const int tid = threadIdx.x;
    if (blockIdx.y == 64) {   // ---- fused wprep: 16 blocks x 1536 elems ----
#pragma unroll
        for (int it = 0; it < 6; ++it) {
            int d = blockIdx.x * 1536 + it * 256 + tid;
            int j = d & 7, oc = (d >> 3) & 127, kg = (d >> 10) & 3, kc = d >> 12;
            int K = kc * 32 + kg * 8 + j;
            int dt = K >> 6, ci = K & 63;
            float wf = tqkw[(oc * 64 + ci) * 3 + dt];
            f16 h = (f16)wf;
            wsplit[d] = h;
            wsplit[24576 + d] = (f16)(wf - (float)h);
        }
        return;
    }
    __shared__ float xs[64][64];
    __shared__ float ws[192][65];
    __shared__ f16 vts[4096];
    const int bt = blockIdx.y, pos0 = blockIdx.x * 64;

    for (int it = 0; it < 16; ++it) {
        int idx = it * 256 + tid;
        int ci = idx >> 6, p = idx & 63;
        xs[ci][p] = x[(bt * 64 + ci) * 1024 + pos0 + p];
    }
    for (int it = 0; it < 48; ++it) {
        int idx = it * 256 + tid;
        ws[idx / 64][idx % 64] = w[idx];
    }
    __syncthreads();

    const int oc = tid & 63, grp = tid >> 6;
    float accq[16], acck[16], accv[16];
    const float bq = bias[oc], bk = bias[64 + oc], bv = bias[128 + oc];
#pragma unroll
    for (int p = 0; p < 16; ++p) { accq[p] = bq; acck[p] = bk; accv[p] = bv; }

    for (int ci = 0; ci < 64; ++ci) {
        float wq = ws[oc][ci], wk = ws[64 + oc][ci], wv = ws[128 + oc][ci];
        const float4* xr = (const float4*)&xs[ci][grp * 16];
#pragma unroll
        for (int p4 = 0; p4 < 4; ++p4) {
            float xa[4];
            *(float4*)xa = xr[p4];
#pragma unroll
            for (int e = 0; e < 4; ++e) {
                int p = p4 * 4 + e;
                accq[p] = fmaf(wq, xa[e], accq[p]);
                acck[p] = fmaf(wk, xa[e], acck[p]);
                accv[p] = fmaf(wv, xa[e], accv[p]);
            }
        }
    }
#pragma unroll
    for (int p = 0; p < 16; ++p) {
        int pos = pos0 + grp * 16 + p;
        int base = (bt * 1024 + pos) * 64 + oc;
        f16 vh = (f16)accv[p];
        q[base] = (f16)(accq[p] * SCALE);
        k[base] = (f16)acck[p];
        v[base] = vh;
        int col = grp * 16 + p;
        *(f16*)((char*)vts + oc * 128 + ((col * 2) ^ sw(oc))) = vh;
    }
    __syncthreads();
#pragma unroll
    for (int it = 0; it < 2; ++it) {
        int s = it * 256 + tid;
        int row = s >> 3, c8 = s & 7;
        f16x8 val = *(const f16x8*)((char*)vts + row * 128 + ((c8 * 16) ^ sw(row)));
        *(f16x8*)(vt + (bt * 64 + row) * 1024 + pos0 + c8 * 8) = val;
    }
}

// ---------------------------------------------------------------------------
// K2a: channel-attention partial dots over 256-pos chunks. grid (pc=4, bt=64).
// ---------------------------------------------------------------------------
__global__ __launch_bounds__(256) void k_chan_part(const f16* __restrict__ q,
                                                   const f16* __restrict__ k,
                                                   float* __restrict__ partials) {
    __shared__ float qs[64][68];
    __shared__ float ks[64][68];
    const int pc = blockIdx.x, bt = blockIdx.y, tid = threadIdx.x;
    const int ti = tid >> 4, tj = tid & 15;
    float acc[4][4] = {{0.f}};

    for (int ch = 0; ch < 4; ++ch) {
        int p0 = pc * 256 + ch * 64;
        __syncthreads();
        for (int it = 0; it < 2; ++it) {
            int e8 = it * 256 + tid;
            int p = e8 >> 3, c8 = e8 & 7;
            f16x8 qv = *(const f16x8*)(q + (bt * 1024 + p0 + p) * 64 + c8 * 8);
            f16x8 kv = *(const f16x8*)(k + (bt * 1024 + p0 + p) * 64 + c8 * 8);
            float4 qlo = make_float4((float)qv[0], (float)qv[1], (float)qv[2], (float)qv[3]);
            float4 qhi = make_float4((float)qv[4], (float)qv[5], (float)qv[6], (float)qv[7]);
            float4 klo = make_float4((float)kv[0], (float)kv[1], (float)kv[2], (float)kv[3]);
            float4 khi = make_float4((float)kv[4], (float)kv[5], (float)kv[6], (float)kv[7]);
            *(float4*)&qs[p][c8 * 8]     = qlo;
            *(float4*)&qs[p][c8 * 8 + 4] = qhi;
            *(float4*)&ks[p][c8 * 8]     = klo;
            *(float4*)&ks[p][c8 * 8 + 4] = khi;
        }
        __syncthreads();
#pragma unroll 8
        for (int p = 0; p < 64; ++p) {
            float qa[4], ka[4];
            *(float4*)qa = *(const float4*)&qs[p][ti * 4];
            *(float4*)ka = *(const float4*)&ks[p][tj * 4];
#pragma unroll
            for (int r = 0; r < 4; ++r)
#pragma unroll
                for (int c = 0; c < 4; ++c)
                    acc[r][c] = fmaf(qa[r], ka[c], acc[r][c]);
        }
    }
#pragma unroll
    for (int r = 0; r < 4; ++r) {
        float4 o4 = make_float4(acc[r][0], acc[r][1], acc[r][2], acc[r][3]);
        *(float4*)&partials[((bt * 4 + pc) * 64 + ti * 4 + r) * 64 + tj * 4] = o4;
    }
}

// K2b: reduce partials + row softmax -> cattn fp16. grid 64 (bt), 256 thr.
__global__ __launch_bounds__(256) void k_chan_red(const float* __restrict__ partials,
                                                  f16* __restrict__ cattn) {
    const int bt = blockIdx.x, tid = threadIdx.x;
    const int i = tid >> 2, q4 = tid & 3;
    float s[16];
#pragma unroll
    for (int jj = 0; jj < 16; ++jj) s[jj] = 0.f;
#pragma unroll
    for (int pc = 0; pc < 4; ++pc) {
        const float4* src = (const float4*)(partials + ((bt * 4 + pc) * 64 + i) * 64 + q4 * 16);
#pragma unroll
        for (int f4 = 0; f4 < 4; ++f4) {
            float a[4];
            *(float4*)a = src[f4];
#pragma unroll
            for (int e = 0; e < 4; ++e) s[f4 * 4 + e] += a[e];
        }
    }
    float m = -1e30f;
#pragma unroll
    for (int jj = 0; jj < 16; ++jj) m = fmaxf(m, s[jj]);
    m = fmaxf(m, __shfl_xor(m, 1, 64));
    m = fmaxf(m, __shfl_xor(m, 2, 64));
    float e[16], sum = 0.f;
#pragma unroll
    for (int jj = 0; jj < 16; ++jj) { e[jj] = __expf(s[jj] - m); sum += e[jj]; }
    sum += __shfl_xor(sum, 1, 64);
    sum += __shfl_xor(sum, 2, 64);
    float inv = 1.f / sum;
    f16x8 o0, o1;
#pragma unroll
    for (int jj = 0; jj < 8; ++jj) { o0[jj] = (f16)(e[jj] * inv); o1[jj] = (f16)(e[8 + jj] * inv); }
    f16* dst = cattn + (bt * 64 + i) * 64 + q4 * 16;
    *(f16x8*)dst = o0;
    *(f16x8*)(dst + 8) = o1;
}

// ---------------------------------------------------------------------------
// K3: pixel flash attention + channel-out, SWAPPED QK^T (lane-local P rows).
// S^T = MFMA(K, Q): lane holds P[qrow = lane&15][j = jt*16 + (lane>>4)*4 + r].
// P packed to b32 pairs -> wave-private LDS [128][36 words] -> b128 A-frags.
// One barrier per chunk; K/vt double-buffered with reg-prefetch.
// ---------------------------------------------------------------------------
__global__ __launch_bounds__(256) void k_pixel(const f16* __restrict__ q,
                                               const f16* __restrict__ k,
                                               const f16* __restrict__ v,
                                               const f16* __restrict__ vt,
                                               const f16* __restrict__ cattn,
                                               f16* __restrict__ xh,
                                               f16* __restrict__ xl) {
    __shared__ f16 kv_s[2][8192];   // [buf][ k: 0..4095 | vt: 4096..8191 ]
    __shared__ char p_raw[18432];   // P region [128 rows][36 words]; also Q/v staging

    const int bt = blockIdx.x, row0 = blockIdx.y * 128;
    const int tid = threadIdx.x;
    const int wv = tid >> 6;
    const int ln = tid & 15;
    const int kgrp = (tid >> 4) & 3;
    const int r2 = tid >> 3, c8 = tid & 7;

    f16x8 k0, k1, v0, v1;
    const f16* kbase = k + bt * 1024 * 64;
    const f16* vtbase = vt + (size_t)bt * 65536;

    auto issue = [&](int ch) {
        const f16* kg = kbase + ch * 64 * 64;
        const f16* vtg = vtbase + ch * 64;
        k0 = *(const f16x8*)(kg + r2 * 64 + c8 * 8);
        k1 = *(const f16x8*)(kg + (r2 + 32) * 64 + c8 * 8);
        v0 = *(const f16x8*)(vtg + r2 * 1024 + c8 * 8);
        v1 = *(const f16x8*)(vtg + (r2 + 32) * 1024 + c8 * 8);
    };
    auto commit = [&](int buf) {
        char* kb = (char*)&kv_s[buf][0];
        char* vb = (char*)&kv_s[buf][4096];
        *(f16x8*)(kb + r2 * 128 + ((c8 * 16) ^ sw(r2))) = k0;
        *(f16x8*)(kb + (r2 + 32) * 128 + ((c8 * 16) ^ sw(r2 + 32))) = k1;
        *(f16x8*)(vb + r2 * 128 + ((c8 * 16) ^ sw(r2))) = v0;
        *(f16x8*)(vb + (r2 + 32) * 128 + ((c8 * 16) ^ sw(r2 + 32))) = v1;
    };

    // ---- prologue: stage Q (into p_raw), read Q frags, commit ch0, issue ch1
    issue(0);
    {
        const f16* qg = q + (bt * 1024 + row0) * 64;
#pragma unroll
        for (int p = 0; p < 4; ++p) {
            int e8 = p * 256 + tid;
            int rr = e8 >> 3, cc = e8 & 7;
            f16x8 val = *(const f16x8*)(qg + rr * 64 + cc * 8);
            *(f16x8*)(p_raw + rr * 128 + ((cc * 16) ^ sw(rr))) = val;
        }
    }
    __syncthreads();
    f16x8 qa[2][2];
#pragma unroll
    for (int rt = 0; rt < 2; ++rt) {
        int rr = rt * 64 + 16 * wv + ln;
#pragma unroll
        for (int kb = 0; kb < 2; ++kb)
            qa[rt][kb] = *(const f16x8*)(p_raw + rr * 128 + (((kb * 4 + kgrp) * 16) ^ sw(rr)));
    }
    commit(0);
    issue(1);
    __syncthreads();

    f32x4 out[2][4];
    float lr[2] = {0.f, 0.f};
#pragma unroll
    for (int rt = 0; rt < 2; ++rt)
#pragma unroll
        for (int ct = 0; ct < 4; ++ct) out[rt][ct] = (f32x4){0.f, 0.f, 0.f, 0.f};

    for (int ch = 0; ch < 16; ++ch) {
        const char* kb = (const char*)&kv_s[ch & 1][0];
        const char* vb = (const char*)&kv_s[ch & 1][4096];

        // K fragments (A operand now)
        f16x8 kf[4][2];
#pragma unroll
        for (int jt = 0; jt < 4; ++jt)
#pragma unroll
            for (int kb2 = 0; kb2 < 2; ++kb2) {
                int jr = jt * 16 + ln;
                kf[jt][kb2] = *(const f16x8*)(kb + jr * 128 + (((kb2 * 4 + kgrp) * 16) ^ sw(jr)));
            }
        // S^T = K Q^T, exp, packed wave-private P store
#pragma unroll
        for (int rt = 0; rt < 2; ++rt) {
            int prow = rt * 64 + wv * 16 + ln;
            char* pb = p_raw + prow * 144;
            f32x4 sx[4];
#pragma unroll
            for (int jt = 0; jt < 4; ++jt) sx[jt] = (f32x4){0.f, 0.f, 0.f, 0.f};
#pragma unroll
            for (int jt = 0; jt < 4; ++jt)
#pragma unroll
                for (int kb2 = 0; kb2 < 2; ++kb2)
                    sx[jt] = MFMA16(kf[jt][kb2], qa[rt][kb2], sx[jt]);
#pragma unroll
            for (int jt = 0; jt < 4; ++jt) {
                float p0 = __expf(sx[jt][0]), p1 = __expf(sx[jt][1]);
                float p2 = __expf(sx[jt][2]), p3 = __expf(sx[jt][3]);
                lr[rt] += (p0 + p1) + (p2 + p3);
                f16x2 w0, w1;
                w0[0] = (f16)p0; w0[1] = (f16)p1;
                w1[0] = (f16)p2; w1[1] = (f16)p3;
                *(f16x2*)(pb + (jt * 8 + kgrp * 2) * 4) = w0;
                *(f16x2*)(pb + (jt * 8 + kgrp * 2 + 1) * 4) = w1;
            }
        }
        // V fragments
        f16x8 vf[4][2];
#pragma unroll
        for (int ct = 0; ct < 4; ++ct)
#pragma unroll
            for (int kb2 = 0; kb2 < 2; ++kb2) {
                int cr = ct * 16 + ln;
                vf[ct][kb2] = *(const f16x8*)(vb + cr * 128 + (((kb2 * 4 + kgrp) * 16) ^ sw(cr)));
            }
        // out += P V  (wave-private rows of p_raw; in-order per-wave LDS pipe)
#pragma unroll
        for (int rt = 0; rt < 2; ++rt) {
            int prow = rt * 64 + wv * 16 + ln;
            f16x8 pa[2];
#pragma unroll
            for (int kb2 = 0; kb2 < 2; ++kb2)
                pa[kb2] = *(const f16x8*)(p_raw + prow * 144 + (kb2 * 16 + kgrp * 4) * 4);
#pragma unroll
            for (int ct = 0; ct < 4; ++ct)
#pragma unroll
                for (int kb2 = 0; kb2 < 2; ++kb2)
                    out[rt][ct] = MFMA16(pa[kb2], vf[ct][kb2], out[rt][ct]);
        }
        if (ch < 15) {
            commit((ch + 1) & 1);
            if (ch < 14) issue(ch + 2);
        }
        __syncthreads();
    }

    // ---- finish softmax: lane has partial for qrow = ln; reduce across kgrp
    float invr[2][4];
#pragma unroll
    for (int rt = 0; rt < 2; ++rt) {
        float l = lr[rt];
        l += __shfl_xor(l, 16, 64);
        l += __shfl_xor(l, 32, 64);
        float inv = 1.f / l;   // lane holds inv for row (16wv + ln) of row-tile rt
#pragma unroll
        for (int r = 0; r < 4; ++r)
            invr[rt][r] = __shfl(inv, kgrp * 4 + r, 64);  // inv for out-row kgrp*4+r
#pragma unroll
        for (int r = 0; r < 4; ++r)
#pragma unroll
            for (int ct = 0; ct < 4; ++ct) out[rt][ct][r] *= invr[rt][r];
    }

    // ---- channel contribution: out[pos][i] += sum_j v[pos][j] * cattn[i][j] ----
    {
        f16* cs = &kv_s[0][0];
        const f16* cg = cattn + bt * 4096;
#pragma unroll
        for (int p = 0; p < 2; ++p) {
            int e8 = p * 256 + tid;
            int rr = e8 >> 3, cc = e8 & 7;
            f16x8 cv = *(const f16x8*)(cg + rr * 64 + cc * 8);
            *(f16x8*)((char*)cs + rr * 128 + ((cc * 16) ^ sw(rr))) = cv;
        }
        const f16* vg = v + (bt * 1024 + row0) * 64;
#pragma unroll
        for (int p = 0; p < 4; ++p) {
            int e8 = p * 256 + tid;
            int rr = e8 >> 3, cc = e8 & 7;
            f16x8 vv = *(const f16x8*)(vg + rr * 64 + cc * 8);
            *(f16x8*)(p_raw + rr * 128 + ((cc * 16) ^ sw(rr))) = vv;
        }
    }
    __syncthreads();
    {
        const char* cs = (const char*)&kv_s[0][0];
        f16x8 cb[4][2];
#pragma unroll
        for (int it = 0; it < 4; ++it)
#pragma unroll
            for (int kb2 = 0; kb2 < 2; ++kb2) {
                int ir = it * 16 + ln;
                cb[it][kb2] = *(const f16x8*)(cs + ir * 128 + (((kb2 * 4 + kgrp) * 16) ^ sw(ir)));
            }
#pragma unroll
        for (int rt = 0; rt < 2; ++rt) {
            int rr = rt * 64 + 16 * wv + ln;
            f16x8 va[2];
#pragma unroll
            for (int kb2 = 0; kb2 < 2; ++kb2)
                va[kb2] = *(const f16x8*)(p_raw + rr * 128 + (((kb2 * 4 + kgrp) * 16) ^ sw(rr)));
#pragma unroll
            for (int it = 0; it < 4; ++it)
#pragma unroll
                for (int kb2 = 0; kb2 < 2; ++kb2)
                    out[rt][it] = MFMA16(va[kb2], cb[it][kb2], out[rt][it]);
        }
    }

    // ---- store xhat as split fp16 ----
#pragma unroll
    for (int rt = 0; rt < 2; ++rt)
#pragma unroll
        for (int ct = 0; ct < 4; ++ct)
#pragma unroll
            for (int r = 0; r < 4; ++r) {
                float val = out[rt][ct][r];
                f16 h = (f16)val;
                int idx = (bt * 1024 + row0 + rt * 64 + 16 * wv + kgrp * 4 + r) * 64 + ct * 16 + ln;
                xh[idx] = h;
                xl[idx] = (f16)(val - (float)h);
            }
}

// ---------------------------------------------------------------------------
// K4: temporal conv (3,1,1) as split-fp16 MFMA GEMM, weights from wsplit.
// ---------------------------------------------------------------------------
__global__ __launch_bounds__(256) void k_tconv(const f16* __restrict__ xh,
                                               const f16* __restrict__ xl,
                                               const f16* __restrict__ wsplit,
                                               const float* __restrict__ bias,
                                               float* __restrict__ tq,
                                               float* __restrict__ tk) {
    __shared__ f16 xs[2][3][4096];
    const int bt = blockIdx.y, pos0 = blockIdx.x * 64;
    const int b = bt >> 3, t = bt & 7;
    const int tid = threadIdx.x;
    const int wvid = tid >> 6, ln = tid & 15, kgrp = (tid >> 4) & 3;

    for (int dt = 0; dt < 3; ++dt) {
        int tt = t + dt - 1;
        bool ok = (tt >= 0) && (tt < 8);
        const f16* srch = xh + ((b * 8 + tt) * 1024 + pos0) * 64;
        const f16* srcl = xl + ((b * 8 + tt) * 1024 + pos0) * 64;
#pragma unroll
        for (int p = 0; p < 2; ++p) {
            int e8 = p * 256 + tid;
            int r2 = e8 >> 3, c8 = e8 & 7;
            f16x8 vh = {0, 0, 0, 0, 0, 0, 0, 0};
            f16x8 vl = {0, 0, 0, 0, 0, 0, 0, 0};
            if (ok) {
                vh = *(const f16x8*)(srch + r2 * 64 + c8 * 8);
                vl = *(const f16x8*)(srcl + r2 * 64 + c8 * 8);
            }
            int byte = r2 * 128 + ((c8 * 16) ^ sw(r2));
            *(f16x8*)((char*)&xs[0][dt][0] + byte) = vh;
            *(f16x8*)((char*)&xs[1][dt][0] + byte) = vl;
        }
    }

    f16x8 bh[2][6], bl[2][6];
#pragma unroll
    for (int og = 0; og < 2; ++og) {
        int oc = wvid * 32 + og * 16 + ln;
#pragma unroll
        for (int kc = 0; kc < 6; ++kc) {
            int idx = (kc * 4 + kgrp) * 1024 + oc * 8;
            bh[og][kc] = *(const f16x8*)(wsplit + idx);
            bl[og][kc] = *(const f16x8*)(wsplit + 24576 + idx);
        }
    }
    __syncthreads();

#pragma unroll
    for (int pg = 0; pg < 4; ++pg) {
        f16x8 ah[6], al[6];
        int rr = pg * 16 + ln;
#pragma unroll
        for (int kc = 0; kc < 6; ++kc) {
            int dt = kc >> 1;
            int ci0 = (kc & 1) * 32 + kgrp * 8;
            int byte = rr * 128 + ((ci0 * 2) ^ sw(rr));
            ah[kc] = *(const f16x8*)((char*)&xs[0][dt][0] + byte);
            al[kc] = *(const f16x8*)((char*)&xs[1][dt][0] + byte);
        }
#pragma unroll
        for (int og = 0; og < 2; ++og) {
            int oc = wvid * 32 + og * 16 + ln;
            float bv = bias[oc];
            f32x4 acc = {bv, bv, bv, bv};
#pragma unroll
            for (int kc = 0; kc < 6; ++kc) {
                acc = MFMA16(ah[kc], bh[og][kc], acc);
                acc = MFMA16(al[kc], bh[og][kc], acc);
                acc = MFMA16(ah[kc], bl[og][kc], acc);
            }
            float* dst = (oc < 64) ? tq : tk;
            int orow = oc & 63;
            int pos = pos0 + pg * 16 + kgrp * 4;
            *(float4*)&dst[(bt * 64 + orow) * 1024 + pos] =
                make_float4(acc[0], acc[1], acc[2], acc[3]);
        }
    }
}

// ---------------------------------------------------------------------------
// K5: temporal dots partials: grid (128 d-chunks of 512, 8 b)
// ---------------------------------------------------------------------------
__global__ __launch_bounds__(256) void k_tdots(const float* __restrict__ tq,
                                               const float* __restrict__ tk,
                                               float* __restrict__ partials) {
    __shared__ float qs[8][516];
    __shared__ float ks[8][516];
    const int ch = blockIdx.x, b = blockIdx.y;
    const int tid = threadIdx.x;
    const int d0 = ch * 512;

    for (int it = 0; it < 4; ++it) {
        int f4 = it * 256 + tid;
        int i = f4 >> 7, d4 = f4 & 127;
        *(float4*)&qs[i][d4 * 4] = *(const float4*)(tq + (size_t)(b * 8 + i) * 65536 + d0 + d4 * 4);
        *(float4*)&ks[i][d4 * 4] = *(const float4*)(tk + (size_t)(b * 8 + i) * 65536 + d0 + d4 * 4);
    }
    __syncthreads();

    const int p = tid >> 2, sub = tid & 3;
    const int i = p >> 3, j = p & 7;
    float acc = 0.f;
#pragma unroll 8
    for (int d4 = 0; d4 < 32; ++d4) {
        int off = (d4 * 4 + sub) * 4;
        float qa[4], ka[4];
        *(float4*)qa = *(const float4*)&qs[i][off];
        *(float4*)ka = *(const float4*)&ks[j][off];
        acc = dp4(qa, ka, acc);
    }
    acc += __shfl_xor(acc, 1, 64);
    acc += __shfl_xor(acc, 2, 64);
    if (sub == 0) partials[(b * 128 + ch) * 64 + p] = acc;
}

// ---------------------------------------------------------------------------
// K7: fused temporal softmax + output. grid (16 pt, 2 kq, 8 b).
// Block computes ta for its 4 kk from partials, then
// out[b*8+kk][cc][pos] = sum_t ta[kk][t] * v[(b*8+t)][pos][cc], v read once.
// ---------------------------------------------------------------------------
__global__ __launch_bounds__(256) void k_tout(const f16* __restrict__ v,
                                              const float* __restrict__ partials,
                                              float* __restrict__ outp) {
    __shared__ float sred[32][9];
    __shared__ float ta_s[4][8];
    __shared__ float ot[64][65];
    const int pt = blockIdx.x, kq = blockIdx.y, b = blockIdx.z;
    const int pos0 = pt * 64;
    const int tid = threadIdx.x;

    // ---- ta for kk = kq*4 .. +3 ----
    {
        const int pair = tid & 31, grp8 = tid >> 5;       // pair = i'*8 + j
        const int i = kq * 4 + (pair >> 3), j = pair & 7;
        float s = 0.f;
#pragma unroll
        for (int c = 0; c < 16; ++c)
            s += partials[(b * 128 + grp8 * 16 + c) * 64 + i * 8 + j];
        sred[pair][grp8] = s;
    }
    __syncthreads();
    if (tid < 32) {
        float t = 0.f;
#pragma unroll
        for (int g = 0; g < 8; ++g) t += sred[tid][g];
        float m = t;
        m = fmaxf(m, __shfl_xor(m, 1, 64));
        m = fmaxf(m, __shfl_xor(m, 2, 64));
        m = fmaxf(m, __shfl_xor(m, 4, 64));
        float e = __expf(t - m);
        float se = e;
        se += __shfl_xor(se, 1, 64);
        se += __shfl_xor(se, 2, 64);
        se += __shfl_xor(se, 4, 64);
        ta_s[tid >> 3][tid & 7] = e / se;
    }
    __syncthreads();

    // ---- weighted sum over t for 4 kk at once ----
    const int cc = tid & 63, grp = tid >> 6;
    float tar[4][8];
#pragma unroll
    for (int kk = 0; kk < 4; ++kk)
#pragma unroll
        for (int t = 0; t < 8; ++t) tar[kk][t] = ta_s[kk][t];
    float acc[4][16];
#pragma unroll
    for (int kk = 0; kk < 4; ++kk)
#pragma unroll
        for (int pp = 0; pp < 16; ++pp) acc[kk][pp] = 0.f;
#pragma unroll
    for (int t = 0; t < 8; ++t) {
        const f16* vb = v + ((size_t)(b * 8 + t) * 1024 + pos0) * 64 + cc;
#pragma unroll
        for (int pp = 0; pp < 16; ++pp) {
            float vv = (float)vb[(grp * 16 + pp) * 64];
#pragma unroll
            for (int kk = 0; kk < 4; ++kk)
                acc[kk][pp] = fmaf(tar[kk][t], vv, acc[kk][pp]);
        }
    }
    // ---- 4 transpose+store rounds ----
#pragma unroll
    for (int kk = 0; kk < 4; ++kk) {
        __syncthreads();
#pragma unroll
        for (int pp = 0; pp < 16; ++pp) ot[cc][grp * 16 + pp] = acc[kk][pp];
        __syncthreads();
        float* dst = outp + ((size_t)(b * 8 + kq * 4 + kk) * 64) * 1024 + pos0;
        for (int it = 0; it < 16; ++it) {
            int idx = it * 256 + tid;
            int c2 = idx >> 6, p2 = idx & 63;
            dst[c2 * 1024 + p2] = ot[c2][p2];
        }
    }
}

// ---------------------------------------------------------------------------
extern "C" void kernel_launch(void* const* d_in, const int* in_sizes, int n_in,
                              void* d_out, int out_size, void* d_ws, size_t ws_size,
                              hipStream_t stream) {
    const float* x     = (const float*)d_in[0];
    const float* qkv_w = (const float*)d_in[1];
    const float* qkv_b = (const float*)d_in[2];
    const float* tqk_w = (const float*)d_in[3];
    const float* tqk_b = (const float*)d_in[4];
    float* outp = (float*)d_out;

    char* wsb = (char*)d_ws;
    f16*   q        = (f16*)wsb;
    f16*   k        = (f16*)(wsb + (8u << 20));
    f16*   v        = (f16*)(wsb + (16u << 20));
    f16*   cattn    = (f16*)(wsb + (24u << 20));
    float* tpart    = (float*)(wsb + (24u << 20) + (1u << 19));
    f16*   wsplit   = (f16*)(wsb + (24u << 20) + (1u << 19) + (1u << 18) + 8192);
    f16*   xhat_hi  = (f16*)(wsb + (25u << 20));
    f16*   xhat_lo  = (f16*)(wsb + (33u << 20));
    float* cpart    = (float*)(wsb + (41u << 20));
    float* tq       = (float*)wsb;                 // overlays q,k (dead after k_pixel)
    float* tk       = (float*)(wsb + (41u << 20));
    f16*   vt       = (f16*)(wsb + (57u << 20));

    k_qkv      <<<dim3(16, 65), 256, 0, stream>>>(x, qkv_w, qkv_b, tqk_w, q, k, v, vt, wsplit);
    k_chan_part<<<dim3(4, 64), 256, 0, stream>>>(q, k, cpart);
    k_chan_red <<<dim3(64), 256, 0, stream>>>(cpart, cattn);
    k_pixel    <<<dim3(64, 8), 256, 0, stream>>>(q, k, v, vt, cattn, xhat_hi, xhat_lo);
    k_tconv    <<<dim3(16, 64), 256, 0, stream>>>(xhat_hi, xhat_lo, wsplit, tqk_b, tq, tk);
    k_tdots    <<<dim3(128, 8), 256, 0, stream>>>(tq, tk, tpart);
    k_tout     <<<dim3(16, 2, 8), 256, 0, stream>>>(v, tpart, outp);
}

// Round 8
// 165.793 us; speedup vs baseline: 3.9148x; 1.0755x over previous
//
#include <hip/hip_runtime.h>

// Problem constants: bt=64, c=64, h=w=32 -> n=1024, t=8, b=8.
#define SCALE 0.125f   // c^-0.5

typedef _Float16 f16;
typedef _Float16 f16x2 __attribute__((ext_vector_type(2)));
typedef _Float16 f16x8 __attribute__((ext_vector_type(8)));
typedef float f32x4 __attribute__((ext_vector_type(4)));

#define MFMA16(A,B,C) __builtin_amdgcn_mfma_f32_16x16x32_f16(A,B,C,0,0,0)

__device__ __forceinline__ float dp4(const float a[4], const float b[4], float acc) {
    acc = fmaf(a[0], b[0], acc);
    acc = fmaf(a[1], b[1], acc);
    acc = fmaf(a[2], b[2], acc);
    acc = fmaf(a[3], b[3], acc);
    return acc;
}

// XOR swizzle for row-major 128B-row f16 tiles: toggles 16B slot.
__device__ __forceinline__ int sw(int row) {
    return ((row & 7) ^ ((row >> 3) & 7)) << 4;
}

// ---------------------------------------------------------------------------
// K1: qkv GEMM -> q (pre-scaled), k, v fp16 token-major + vt channel-major.
// blockIdx.y == 64: conv-weight split prep (fused k_wprep).
// ---------------------------------------------------------------------------
__global__ __launch_bounds__(256) void k_qkv(const float* __restrict__ x,
                                             const float* __restrict__ w,
                                             const float* __restrict__ bias,
                                             const float* __restrict__ tqkw,
                                             f16* __restrict__ q,
                                             f16* __restrict__ k,
                                             f16* __restrict__ v,
                                             f16* __restrict__ vt,
                                             f16* __restrict__ wsplit) {
    const int tid = threadIdx.x;
    if (blockIdx.y == 64) {   // ---- fused wprep: 16 blocks x 1536 elems ----
#pragma unroll
        for (int it = 0; it < 6; ++it) {
            int d = blockIdx.x * 1536 + it * 256 + tid;
            int j = d & 7, oc = (d >> 3) & 127, kg = (d >> 10) & 3, kc = d >> 12;
            int K = kc * 32 + kg * 8 + j;
            int dt = K >> 6, ci = K & 63;
            float wf = tqkw[(oc * 64 + ci) * 3 + dt];
            f16 h = (f16)wf;
            wsplit[d] = h;
            wsplit[24576 + d] = (f16)(wf - (float)h);
        }
        return;
    }
    __shared__ float xs[64][64];
    __shared__ float ws[192][65];
    __shared__ f16 vts[4096];
    const int bt = blockIdx.y, pos0 = blockIdx.x * 64;

    for (int it = 0; it < 16; ++it) {
        int idx = it * 256 + tid;
        int ci = idx >> 6, p = idx & 63;
        xs[ci][p] = x[(bt * 64 + ci) * 1024 + pos0 + p];
    }
    for (int it = 0; it < 48; ++it) {
        int idx = it * 256 + tid;
        ws[idx / 64][idx % 64] = w[idx];
    }
    __syncthreads();

    const int oc = tid & 63, grp = tid >> 6;
    float accq[16], acck[16], accv[16];
    const float bq = bias[oc], bk = bias[64 + oc], bv = bias[128 + oc];
#pragma unroll
    for (int p = 0; p < 16; ++p) { accq[p] = bq; acck[p] = bk; accv[p] = bv; }

    for (int ci = 0; ci < 64; ++ci) {
        float wq = ws[oc][ci], wk = ws[64 + oc][ci], wv = ws[128 + oc][ci];
        const float4* xr = (const float4*)&xs[ci][grp * 16];
#pragma unroll
        for (int p4 = 0; p4 < 4; ++p4) {
            float xa[4];
            *(float4*)xa = xr[p4];
#pragma unroll
            for (int e = 0; e < 4; ++e) {
                int p = p4 * 4 + e;
                accq[p] = fmaf(wq, xa[e], accq[p]);
                acck[p] = fmaf(wk, xa[e], acck[p]);
                accv[p] = fmaf(wv, xa[e], accv[p]);
            }
        }
    }
#pragma unroll
    for (int p = 0; p < 16; ++p) {
        int pos = pos0 + grp * 16 + p;
        int base = (bt * 1024 + pos) * 64 + oc;
        f16 vh = (f16)accv[p];
        q[base] = (f16)(accq[p] * SCALE);
        k[base] = (f16)acck[p];
        v[base] = vh;
        int col = grp * 16 + p;
        *(f16*)((char*)vts + oc * 128 + ((col * 2) ^ sw(oc))) = vh;
    }
    __syncthreads();
#pragma unroll
    for (int it = 0; it < 2; ++it) {
        int s = it * 256 + tid;
        int row = s >> 3, c8 = s & 7;
        f16x8 val = *(const f16x8*)((char*)vts + row * 128 + ((c8 * 16) ^ sw(row)));
        *(f16x8*)(vt + (bt * 64 + row) * 1024 + pos0 + c8 * 8) = val;
    }
}

// ---------------------------------------------------------------------------
// K2a: channel-attention partial dots over 256-pos chunks. grid (pc=4, bt=64).
// ---------------------------------------------------------------------------
__global__ __launch_bounds__(256) void k_chan_part(const f16* __restrict__ q,
                                                   const f16* __restrict__ k,
                                                   float* __restrict__ partials) {
    __shared__ float qs[64][68];
    __shared__ float ks[64][68];
    const int pc = blockIdx.x, bt = blockIdx.y, tid = threadIdx.x;
    const int ti = tid >> 4, tj = tid & 15;
    float acc[4][4] = {{0.f}};

    for (int ch = 0; ch < 4; ++ch) {
        int p0 = pc * 256 + ch * 64;
        __syncthreads();
        for (int it = 0; it < 2; ++it) {
            int e8 = it * 256 + tid;
            int p = e8 >> 3, c8 = e8 & 7;
            f16x8 qv = *(const f16x8*)(q + (bt * 1024 + p0 + p) * 64 + c8 * 8);
            f16x8 kv = *(const f16x8*)(k + (bt * 1024 + p0 + p) * 64 + c8 * 8);
            float4 qlo = make_float4((float)qv[0], (float)qv[1], (float)qv[2], (float)qv[3]);
            float4 qhi = make_float4((float)qv[4], (float)qv[5], (float)qv[6], (float)qv[7]);
            float4 klo = make_float4((float)kv[0], (float)kv[1], (float)kv[2], (float)kv[3]);
            float4 khi = make_float4((float)kv[4], (float)kv[5], (float)kv[6], (float)kv[7]);
            *(float4*)&qs[p][c8 * 8]     = qlo;
            *(float4*)&qs[p][c8 * 8 + 4] = qhi;
            *(float4*)&ks[p][c8 * 8]     = klo;
            *(float4*)&ks[p][c8 * 8 + 4] = khi;
        }
        __syncthreads();
#pragma unroll 8
        for (int p = 0; p < 64; ++p) {
            float qa[4], ka[4];
            *(float4*)qa = *(const float4*)&qs[p][ti * 4];
            *(float4*)ka = *(const float4*)&ks[p][tj * 4];
#pragma unroll
            for (int r = 0; r < 4; ++r)
#pragma unroll
                for (int c = 0; c < 4; ++c)
                    acc[r][c] = fmaf(qa[r], ka[c], acc[r][c]);
        }
    }
#pragma unroll
    for (int r = 0; r < 4; ++r) {
        float4 o4 = make_float4(acc[r][0], acc[r][1], acc[r][2], acc[r][3]);
        *(float4*)&partials[((bt * 4 + pc) * 64 + ti * 4 + r) * 64 + tj * 4] = o4;
    }
}

// K2b: reduce partials + row softmax -> cattn fp16. grid 64 (bt), 256 thr.
__global__ __launch_bounds__(256) void k_chan_red(const float* __restrict__ partials,
                                                  f16* __restrict__ cattn) {
    const int bt = blockIdx.x, tid = threadIdx.x;
    const int i = tid >> 2, q4 = tid & 3;
    float s[16];
#pragma unroll
    for (int jj = 0; jj < 16; ++jj) s[jj] = 0.f;
#pragma unroll
    for (int pc = 0; pc < 4; ++pc) {
        const float4* src = (const float4*)(partials + ((bt * 4 + pc) * 64 + i) * 64 + q4 * 16);
#pragma unroll
        for (int f4 = 0; f4 < 4; ++f4) {
            float a[4];
            *(float4*)a = src[f4];
#pragma unroll
            for (int e = 0; e < 4; ++e) s[f4 * 4 + e] += a[e];
        }
    }
    float m = -1e30f;
#pragma unroll
    for (int jj = 0; jj < 16; ++jj) m = fmaxf(m, s[jj]);
    m = fmaxf(m, __shfl_xor(m, 1, 64));
    m = fmaxf(m, __shfl_xor(m, 2, 64));
    float e[16], sum = 0.f;
#pragma unroll
    for (int jj = 0; jj < 16; ++jj) { e[jj] = __expf(s[jj] - m); sum += e[jj]; }
    sum += __shfl_xor(sum, 1, 64);
    sum += __shfl_xor(sum, 2, 64);
    float inv = 1.f / sum;
    f16x8 o0, o1;
#pragma unroll
    for (int jj = 0; jj < 8; ++jj) { o0[jj] = (f16)(e[jj] * inv); o1[jj] = (f16)(e[8 + jj] * inv); }
    f16* dst = cattn + (bt * 64 + i) * 64 + q4 * 16;
    *(f16x8*)dst = o0;
    *(f16x8*)(dst + 8) = o1;
}

// ---------------------------------------------------------------------------
// K3: pixel flash attention + channel-out, swapped QK^T, P in standard
// 128B-row swizzled layout (f16x2 writes, b128 reads). One barrier/chunk.
// ---------------------------------------------------------------------------
__global__ __launch_bounds__(256) void k_pixel(const f16* __restrict__ q,
                                               const f16* __restrict__ k,
                                               const f16* __restrict__ v,
                                               const f16* __restrict__ vt,
                                               const f16* __restrict__ cattn,
                                               f16* __restrict__ xh,
                                               f16* __restrict__ xl) {
    __shared__ f16 kv_s[2][8192];   // [buf][ k: 0..4095 | vt: 4096..8191 ]
    __shared__ char p_raw[16384];   // Q staging -> P tiles -> v staging (128 rows x 128B)

    const int bt = blockIdx.x, row0 = blockIdx.y * 128;
    const int tid = threadIdx.x;
    const int wv = tid >> 6;
    const int ln = tid & 15;
    const int kgrp = (tid >> 4) & 3;
    const int r2 = tid >> 3, c8 = tid & 7;

    f16x8 k0, k1, v0, v1;
    const f16* kbase = k + bt * 1024 * 64;
    const f16* vtbase = vt + (size_t)bt * 65536;

    auto issue = [&](int ch) {
        const f16* kg = kbase + ch * 64 * 64;
        const f16* vtg = vtbase + ch * 64;
        k0 = *(const f16x8*)(kg + r2 * 64 + c8 * 8);
        k1 = *(const f16x8*)(kg + (r2 + 32) * 64 + c8 * 8);
        v0 = *(const f16x8*)(vtg + r2 * 1024 + c8 * 8);
        v1 = *(const f16x8*)(vtg + (r2 + 32) * 1024 + c8 * 8);
    };
    auto commit = [&](int buf) {
        char* kb = (char*)&kv_s[buf][0];
        char* vb = (char*)&kv_s[buf][4096];
        *(f16x8*)(kb + r2 * 128 + ((c8 * 16) ^ sw(r2))) = k0;
        *(f16x8*)(kb + (r2 + 32) * 128 + ((c8 * 16) ^ sw(r2 + 32))) = k1;
        *(f16x8*)(vb + r2 * 128 + ((c8 * 16) ^ sw(r2))) = v0;
        *(f16x8*)(vb + (r2 + 32) * 128 + ((c8 * 16) ^ sw(r2 + 32))) = v1;
    };

    // ---- prologue ----
    issue(0);
    {
        const f16* qg = q + (bt * 1024 + row0) * 64;
#pragma unroll
        for (int p = 0; p < 4; ++p) {
            int e8 = p * 256 + tid;
            int rr = e8 >> 3, cc = e8 & 7;
            f16x8 val = *(const f16x8*)(qg + rr * 64 + cc * 8);
            *(f16x8*)(p_raw + rr * 128 + ((cc * 16) ^ sw(rr))) = val;
        }
    }
    __syncthreads();
    f16x8 qa[2][2];
#pragma unroll
    for (int rt = 0; rt < 2; ++rt) {
        int rr = rt * 64 + 16 * wv + ln;
#pragma unroll
        for (int kb = 0; kb < 2; ++kb)
            qa[rt][kb] = *(const f16x8*)(p_raw + rr * 128 + (((kb * 4 + kgrp) * 16) ^ sw(rr)));
    }
    commit(0);
    issue(1);
    __syncthreads();

    f32x4 out[2][4];
    float lr[2] = {0.f, 0.f};
#pragma unroll
    for (int rt = 0; rt < 2; ++rt)
#pragma unroll
        for (int ct = 0; ct < 4; ++ct) out[rt][ct] = (f32x4){0.f, 0.f, 0.f, 0.f};

    for (int ch = 0; ch < 16; ++ch) {
        const char* kb = (const char*)&kv_s[ch & 1][0];
        const char* vb = (const char*)&kv_s[ch & 1][4096];

        f16x8 kf[4][2];
#pragma unroll
        for (int jt = 0; jt < 4; ++jt)
#pragma unroll
            for (int kb2 = 0; kb2 < 2; ++kb2) {
                int jr = jt * 16 + ln;
                kf[jt][kb2] = *(const f16x8*)(kb + jr * 128 + (((kb2 * 4 + kgrp) * 16) ^ sw(jr)));
            }
        // S^T = K Q^T; lane (ln,kgrp) holds P[q=ln][j=jt*16+kgrp*4+r]
#pragma unroll
        for (int rt = 0; rt < 2; ++rt) {
            int prow = rt * 64 + wv * 16 + ln;
            char* pb = p_raw + prow * 128;
            const int swz = sw(prow);
            f32x4 sx[4];
#pragma unroll
            for (int jt = 0; jt < 4; ++jt) sx[jt] = (f32x4){0.f, 0.f, 0.f, 0.f};
#pragma unroll
            for (int jt = 0; jt < 4; ++jt)
#pragma unroll
                for (int kb2 = 0; kb2 < 2; ++kb2)
                    sx[jt] = MFMA16(kf[jt][kb2], qa[rt][kb2], sx[jt]);
#pragma unroll
            for (int jt = 0; jt < 4; ++jt) {
                float p0 = __expf(sx[jt][0]), p1 = __expf(sx[jt][1]);
                float p2 = __expf(sx[jt][2]), p3 = __expf(sx[jt][3]);
                lr[rt] += (p0 + p1) + (p2 + p3);
                f16x2 w0, w1;
                w0[0] = (f16)p0; w0[1] = (f16)p1;
                w1[0] = (f16)p2; w1[1] = (f16)p3;
                int base = (jt * 32 + kgrp * 8) ^ swz;
                *(f16x2*)(pb + base) = w0;
                *(f16x2*)(pb + base + 4) = w1;
            }
        }
        f16x8 vf[4][2];
#pragma unroll
        for (int ct = 0; ct < 4; ++ct)
#pragma unroll
            for (int kb2 = 0; kb2 < 2; ++kb2) {
                int cr = ct * 16 + ln;
                vf[ct][kb2] = *(const f16x8*)(vb + cr * 128 + (((kb2 * 4 + kgrp) * 16) ^ sw(cr)));
            }
        // out += P V (wave-private rows of p_raw)
#pragma unroll
        for (int rt = 0; rt < 2; ++rt) {
            int prow = rt * 64 + wv * 16 + ln;
            const int swz = sw(prow);
            f16x8 pa[2];
#pragma unroll
            for (int kb2 = 0; kb2 < 2; ++kb2)
                pa[kb2] = *(const f16x8*)(p_raw + prow * 128 + ((kb2 * 64 + kgrp * 16) ^ swz));
#pragma unroll
            for (int ct = 0; ct < 4; ++ct)
#pragma unroll
                for (int kb2 = 0; kb2 < 2; ++kb2)
                    out[rt][ct] = MFMA16(pa[kb2], vf[ct][kb2], out[rt][ct]);
        }
        if (ch < 15) {
            commit((ch + 1) & 1);
            if (ch < 14) issue(ch + 2);
        }
        __syncthreads();
    }

    // ---- finish softmax: lane's lr is partial for q-row=ln; reduce across kgrp
    float invr[2][4];
#pragma unroll
    for (int rt = 0; rt < 2; ++rt) {
        float l = lr[rt];
        l += __shfl_xor(l, 16, 64);
        l += __shfl_xor(l, 32, 64);
        float inv = 1.f / l;
#pragma unroll
        for (int r = 0; r < 4; ++r)
            invr[rt][r] = __shfl(inv, kgrp * 4 + r, 64);
#pragma unroll
        for (int r = 0; r < 4; ++r)
#pragma unroll
            for (int ct = 0; ct < 4; ++ct) out[rt][ct][r] *= invr[rt][r];
    }

    // ---- channel contribution ----
    {
        f16* cs = &kv_s[0][0];
        const f16* cg = cattn + bt * 4096;
#pragma unroll
        for (int p = 0; p < 2; ++p) {
            int e8 = p * 256 + tid;
            int rr = e8 >> 3, cc = e8 & 7;
            f16x8 cv = *(const f16x8*)(cg + rr * 64 + cc * 8);
            *(f16x8*)((char*)cs + rr * 128 + ((cc * 16) ^ sw(rr))) = cv;
        }
        const f16* vg = v + (bt * 1024 + row0) * 64;
#pragma unroll
        for (int p = 0; p < 4; ++p) {
            int e8 = p * 256 + tid;
            int rr = e8 >> 3, cc = e8 & 7;
            f16x8 vv = *(const f16x8*)(vg + rr * 64 + cc * 8);
            *(f16x8*)(p_raw + rr * 128 + ((cc * 16) ^ sw(rr))) = vv;
        }
    }
    __syncthreads();
    {
        const char* cs = (const char*)&kv_s[0][0];
        f16x8 cb[4][2];
#pragma unroll
        for (int it = 0; it < 4; ++it)
#pragma unroll
            for (int kb2 = 0; kb2 < 2; ++kb2) {
                int ir = it * 16 + ln;
                cb[it][kb2] = *(const f16x8*)(cs + ir * 128 + (((kb2 * 4 + kgrp) * 16) ^ sw(ir)));
            }
#pragma unroll
        for (int rt = 0; rt < 2; ++rt) {
            int rr = rt * 64 + 16 * wv + ln;
            f16x8 va[2];
#pragma unroll
            for (int kb2 = 0; kb2 < 2; ++kb2)
                va[kb2] = *(const f16x8*)(p_raw + rr * 128 + (((kb2 * 4 + kgrp) * 16) ^ sw(rr)));
#pragma unroll
            for (int it = 0; it < 4; ++it)
#pragma unroll
                for (int kb2 = 0; kb2 < 2; ++kb2)
                    out[rt][it] = MFMA16(va[kb2], cb[it][kb2], out[rt][it]);
        }
    }

    // ---- store xhat as split fp16 ----
#pragma unroll
    for (int rt = 0; rt < 2; ++rt)
#pragma unroll
        for (int ct = 0; ct < 4; ++ct)
#pragma unroll
            for (int r = 0; r < 4; ++r) {
                float val = out[rt][ct][r];
                f16 h = (f16)val;
                int idx = (bt * 1024 + row0 + rt * 64 + 16 * wv + kgrp * 4 + r) * 64 + ct * 16 + ln;
                xh[idx] = h;
                xl[idx] = (f16)(val - (float)h);
            }
}

// ---------------------------------------------------------------------------
// K4: FUSED temporal conv + dots. grid (pt=32 pos-tiles of 32, b=8).
// Conv: split-fp16 MFMA over sliding 3-slot xhat ring; tq/tk tiles -> LDS f32
// [8t][32pos][65]. Dots: partials[b][pt][i*8+j] = sum_{d in tile} tq_i . tk_j.
// Dynamic LDS 157696 B.
// ---------------------------------------------------------------------------
__global__ __launch_bounds__(256) void k_tcd(const f16* __restrict__ xh,
                                             const f16* __restrict__ xl,
                                             const f16* __restrict__ wsplit,
                                             const float* __restrict__ bias,
                                             float* __restrict__ partials) {
    extern __shared__ char lds[];
    float* tqs = (float*)lds;                    // [8][32*65] = 66560 B
    float* tks = (float*)(lds + 66560);          // [8][32*65]
    f16*   xst = (f16*)(lds + 133120);           // [hiLo*3+slot][2048] = 24576 B
    const int pt = blockIdx.x, b = blockIdx.y;
    const int tid = threadIdx.x;
    const int wvid = tid >> 6, ln = tid & 15, kgrp = (tid >> 4) & 3;

    // ---- weight fragments (coalesced, fragment-ordered) ----
    f16x8 bh[2][6], bl[2][6];
#pragma unroll
    for (int og = 0; og < 2; ++og) {
        int oc = wvid * 32 + og * 16 + ln;
#pragma unroll
        for (int kc = 0; kc < 6; ++kc) {
            int idx = (kc * 4 + kgrp) * 1024 + oc * 8;
            bh[og][kc] = *(const f16x8*)(wsplit + idx);
            bl[og][kc] = *(const f16x8*)(wsplit + 24576 + idx);
        }
    }

    const int srow = tid >> 3, sc8 = tid & 7;    // staging coords (32 rows x 8 c8)
    auto stage = [&](int tt) {
        int s = tt % 3;
        size_t goff = ((size_t)(b * 8 + tt) * 1024 + pt * 32 + srow) * 64 + sc8 * 8;
        f16x8 vh = *(const f16x8*)(xh + goff);
        f16x8 vl = *(const f16x8*)(xl + goff);
        int byte = srow * 128 + ((sc8 * 16) ^ sw(srow));
        *(f16x8*)((char*)(xst + s * 2048) + byte) = vh;
        *(f16x8*)((char*)(xst + (3 + s) * 2048) + byte) = vl;
    };

    stage(0);
    for (int t = 0; t < 8; ++t) {
        if (t + 1 < 8) stage(t + 1);
        __syncthreads();
#pragma unroll
        for (int pg = 0; pg < 2; ++pg) {
            f16x8 ah[6], al[6];
            bool valid[6];
            int rr = pg * 16 + ln;
#pragma unroll
            for (int kc = 0; kc < 6; ++kc) {
                int dt = kc >> 1;
                int tt = t + dt - 1;
                valid[kc] = (tt >= 0) && (tt < 8);
                if (valid[kc]) {
                    int s = tt % 3;
                    int ci0 = (kc & 1) * 32 + kgrp * 8;
                    int byte = rr * 128 + ((ci0 * 2) ^ sw(rr));
                    ah[kc] = *(const f16x8*)((char*)(xst + s * 2048) + byte);
                    al[kc] = *(const f16x8*)((char*)(xst + (3 + s) * 2048) + byte);
                } else {
                    ah[kc] = (f16x8){0,0,0,0,0,0,0,0};
                    al[kc] = (f16x8){0,0,0,0,0,0,0,0};
                }
            }
#pragma unroll
            for (int og = 0; og < 2; ++og) {
                int oc = wvid * 32 + og * 16 + ln;
                float bv = bias[oc];
                f32x4 acc = {bv, bv, bv, bv};
#pragma unroll
                for (int kc = 0; kc < 6; ++kc) {
                    if (valid[kc]) {
                        acc = MFMA16(ah[kc], bh[og][kc], acc);
                        acc = MFMA16(al[kc], bh[og][kc], acc);
                        acc = MFMA16(ah[kc], bl[og][kc], acc);
                    }
                }
                float* dst = (oc < 64) ? tqs : tks;
                int c = oc & 63;
                int posb = pg * 16 + kgrp * 4;
#pragma unroll
                for (int r = 0; r < 4; ++r)
                    dst[t * 2080 + (posb + r) * 65 + c] = acc[r];
            }
        }
        __syncthreads();
    }

    // ---- dots: thread owns d-slice (pos = tid>>3, c = (tid&7)*8 .. +7) ----
    const int dpos = tid >> 3, dc0 = (tid & 7) * 8;
    float tqa[8][8];
#pragma unroll
    for (int i = 0; i < 8; ++i) {
        const float* src = tqs + i * 2080 + dpos * 65 + dc0;
#pragma unroll
        for (int e = 0; e < 8; ++e) tqa[i][e] = src[e];
    }
    float part[8][8];
#pragma unroll
    for (int i = 0; i < 8; ++i)
#pragma unroll
        for (int j = 0; j < 8; ++j) part[i][j] = 0.f;
#pragma unroll
    for (int j = 0; j < 8; ++j) {
        float tkb[8];
        const float* src = tks + j * 2080 + dpos * 65 + dc0;
#pragma unroll
        for (int e = 0; e < 8; ++e) tkb[e] = src[e];
#pragma unroll
        for (int i = 0; i < 8; ++i)
#pragma unroll
            for (int e = 0; e < 8; ++e)
                part[i][j] = fmaf(tqa[i][e], tkb[e], part[i][j]);
    }
    __syncthreads();   // all tqs/tks reads done; reuse LDS for reduction
    float* red2 = (float*)lds;              // [64 pairs][257]
    float* sred = (float*)(lds + 66560);    // [64][4]
#pragma unroll
    for (int i = 0; i < 8; ++i)
#pragma unroll
        for (int j = 0; j < 8; ++j)
            red2[(i * 8 + j) * 257 + tid] = part[i][j];
    __syncthreads();
    {
        int pair = tid & 63, q4 = tid >> 6;
        float s = 0.f;
        const float* src = red2 + pair * 257 + q4 * 64;
        for (int c = 0; c < 64; ++c) s += src[c];
        sred[pair * 4 + q4] = s;
    }
    __syncthreads();
    if (tid < 64)
        partials[(b * 32 + pt) * 64 + tid] =
            sred[tid * 4] + sred[tid * 4 + 1] + sred[tid * 4 + 2] + sred[tid * 4 + 3];
}

// ---------------------------------------------------------------------------
// K7: fused temporal softmax + output. grid (16 pt, 2 kq, 8 b).
// partials layout: [b][32 chunks][64 pairs]
// ---------------------------------------------------------------------------
__global__ __launch_bounds__(256) void k_tout(const f16* __restrict__ v,
                                              const float* __restrict__ partials,
                                              float* __restrict__ outp) {
    __shared__ float sred[32][9];
    __shared__ float ta_s[4][8];
    __shared__ float ot[64][65];
    const int pt = blockIdx.x, kq = blockIdx.y, b = blockIdx.z;
    const int pos0 = pt * 64;
    const int tid = threadIdx.x;

    {
        const int pair = tid & 31, grp8 = tid >> 5;
        const int i = kq * 4 + (pair >> 3), j = pair & 7;
        float s = 0.f;
#pragma unroll
        for (int c = 0; c < 4; ++c)
            s += partials[(b * 32 + grp8 * 4 + c) * 64 + i * 8 + j];
        sred[pair][grp8] = s;
    }
    __syncthreads();
    if (tid < 32) {
        float t = 0.f;
#pragma unroll
        for (int g = 0; g < 8; ++g) t += sred[tid][g];
        float m = t;
        m = fmaxf(m, __shfl_xor(m, 1, 64));
        m = fmaxf(m, __shfl_xor(m, 2, 64));
        m = fmaxf(m, __shfl_xor(m, 4, 64));
        float e = __expf(t - m);
        float se = e;
        se += __shfl_xor(se, 1, 64);
        se += __shfl_xor(se, 2, 64);
        se += __shfl_xor(se, 4, 64);
        ta_s[tid >> 3][tid & 7] = e / se;
    }
    __syncthreads();

    const int cc = tid & 63, grp = tid >> 6;
    float tar[4][8];
#pragma unroll
    for (int kk = 0; kk < 4; ++kk)
#pragma unroll
        for (int t = 0; t < 8; ++t) tar[kk][t] = ta_s[kk][t];
    float acc[4][16];
#pragma unroll
    for (int kk = 0; kk < 4; ++kk)
#pragma unroll
        for (int pp = 0; pp < 16; ++pp) acc[kk][pp] = 0.f;
#pragma unroll
    for (int t = 0; t < 8; ++t) {
        const f16* vb = v + ((size_t)(b * 8 + t) * 1024 + pos0) * 64 + cc;
#pragma unroll
        for (int pp = 0; pp < 16; ++pp) {
            float vv = (float)vb[(grp * 16 + pp) * 64];
#pragma unroll
            for (int kk = 0; kk < 4; ++kk)
                acc[kk][pp] = fmaf(tar[kk][t], vv, acc[kk][pp]);
        }
    }
#pragma unroll
    for (int kk = 0; kk < 4; ++kk) {
        __syncthreads();
#pragma unroll
        for (int pp = 0; pp < 16; ++pp) ot[cc][grp * 16 + pp] = acc[kk][pp];
        __syncthreads();
        float* dst = outp + ((size_t)(b * 8 + kq * 4 + kk) * 64) * 1024 + pos0;
        for (int it = 0; it < 16; ++it) {
            int idx = it * 256 + tid;
            int c2 = idx >> 6, p2 = idx & 63;
            dst[c2 * 1024 + p2] = ot[c2][p2];
        }
    }
}

// ---------------------------------------------------------------------------
extern "C" void kernel_launch(void* const* d_in, const int* in_sizes, int n_in,
                              void* d_out, int out_size, void* d_ws, size_t ws_size,
                              hipStream_t stream) {
    const float* x     = (const float*)d_in[0];
    const float* qkv_w = (const float*)d_in[1];
    const float* qkv_b = (const float*)d_in[2];
    const float* tqk_w = (const float*)d_in[3];
    const float* tqk_b = (const float*)d_in[4];
    float* outp = (float*)d_out;

    char* wsb = (char*)d_ws;
    f16*   q        = (f16*)wsb;
    f16*   k        = (f16*)(wsb + (8u << 20));
    f16*   v        = (f16*)(wsb + (16u << 20));
    f16*   cattn    = (f16*)(wsb + (24u << 20));
    float* tpart    = (float*)(wsb + (24u << 20) + (1u << 19));
    f16*   wsplit   = (f16*)(wsb + (24u << 20) + (1u << 19) + (1u << 18) + 8192);
    f16*   xhat_hi  = (f16*)(wsb + (25u << 20));
    f16*   xhat_lo  = (f16*)(wsb + (33u << 20));
    float* cpart    = (float*)(wsb + (41u << 20));
    f16*   vt       = (f16*)(wsb + (57u << 20));

    hipFuncSetAttribute((const void*)k_tcd,
                        hipFuncAttributeMaxDynamicSharedMemorySize, 157696);

    k_qkv      <<<dim3(16, 65), 256, 0, stream>>>(x, qkv_w, qkv_b, tqk_w, q, k, v, vt, wsplit);
    k_chan_part<<<dim3(4, 64), 256, 0, stream>>>(q, k, cpart);
    k_chan_red <<<dim3(64), 256, 0, stream>>>(cpart, cattn);
    k_pixel    <<<dim3(64, 8), 256, 0, stream>>>(q, k, v, vt, cattn, xhat_hi, xhat_lo);
    k_tcd      <<<dim3(32, 8), 256, 157696, stream>>>(xhat_hi, xhat_lo, wsplit, tqk_b, tpart);
    k_tout     <<<dim3(16, 2, 8), 256, 0, stream>>>(v, tpart, outp);
}